// Round 1
// baseline (9038.785 us; speedup 1.0000x reference)
//
#include <hip/hip_runtime.h>
#include <hip/hip_bf16.h>
#include <cstddef>

// ---------------- problem constants ----------------
constexpr int cN_LOW  = 20000;
constexpr int cN_HIGH = 150000;
constexpr int cSEQ = 25;
constexpr int cHIN = 25;
constexpr int cHHID = 25;
constexpr int cENC = 32;
constexpr int cHIGH_IN = 7;
constexpr int cD = 16;
constexpr int cNL = 5;
constexpr int cE_L2H = 1350000;
constexpr int cE_HH = 1200000;
constexpr int cE_TOT = cE_HH + cN_HIGH;   // hh edges + self loops = 1350000
constexpr float cEPS = 1e-5f;
constexpr float cSLOPE = 0.2f;
constexpr float INV_NLOW  = 1.0f / (float)cN_LOW;
constexpr float INV_NHIGH = 1.0f / (float)cN_HIGH;

// ---------------- workspace layout (float offsets) ----------------
constexpr size_t OFF_HS   = 0;                                  // [N_LOW*625]
constexpr size_t SZ_HS    = (size_t)cN_LOW * 625;
constexpr size_t OFF_ENC  = OFF_HS + SZ_HS;                     // [N_LOW*32]
constexpr size_t SZ_ENC   = (size_t)cN_LOW * cENC;
constexpr size_t OFF_AGG  = OFF_ENC + SZ_ENC;                   // [N_HIGH*32]
constexpr size_t SZ_AGG   = (size_t)cN_HIGH * cENC;
constexpr size_t OFF_CNTL = OFF_AGG + SZ_AGG;                   // [N_HIGH]
constexpr size_t OFF_CNTH = OFF_CNTL + cN_HIGH;                 // [N_HIGH]
constexpr size_t OFF_XA   = OFF_CNTH + cN_HIGH;                 // [N_HIGH*16]
constexpr size_t OFF_XB   = OFF_XA + (size_t)cN_HIGH * cD;      // [N_HIGH*16]
constexpr size_t OFF_XL   = OFF_XB + (size_t)cN_HIGH * cD;      // [N_HIGH*16]
constexpr size_t OFF_XR   = OFF_XL + (size_t)cN_HIGH * cD;      // [N_HIGH*16]
constexpr size_t OFF_EX   = OFF_XR + (size_t)cN_HIGH * cD;      // [E_TOT]
constexpr size_t OFF_DEN  = OFF_EX + (size_t)cE_TOT;            // [N_HIGH]
constexpr size_t OFF_STAT = OFF_DEN + cN_HIGH;                  // [64 enc + 5*32 layer stats]
// total ~29.34M floats ~ 117.4 MB

// ---------------- GRU kernel ----------------
// block: 10 nodes x 25 hidden units = 250 threads. grid: 20000/10 = 2000
constexpr int GRU_NODES = 10;
constexpr int GRU_BLOCK = GRU_NODES * cHHID;   // 250

__global__ void k_gru(const float* __restrict__ x_low,
                      const float* __restrict__ Wih, const float* __restrict__ Whh,
                      const float* __restrict__ bih, const float* __restrict__ bhh,
                      float* __restrict__ hs) {
  __shared__ float sWih[75 * 25];
  __shared__ float sWhh[75 * 25];
  __shared__ float sbih[75], sbhh[75];
  __shared__ float sx[GRU_NODES][cHIN];
  __shared__ float sh[GRU_NODES][cHHID];

  int tid = threadIdx.x;
  for (int i = tid; i < 75 * 25; i += GRU_BLOCK) { sWih[i] = Wih[i]; sWhh[i] = Whh[i]; }
  for (int i = tid; i < 75; i += GRU_BLOCK) { sbih[i] = bih[i]; sbhh[i] = bhh[i]; }

  int nl = tid / cHHID;           // 0..9
  int j  = tid % cHHID;           // 0..24
  int n  = blockIdx.x * GRU_NODES + nl;
  sh[nl][j] = 0.0f;
  __syncthreads();

  const float* xrow = x_low + (size_t)n * 625;
  float* hrow = hs + (size_t)n * 625;
  float bihr = sbih[j], bihz = sbih[25 + j], bihn = sbih[50 + j];
  float bhhr = sbhh[j], bhhz = sbhh[25 + j], bhhn = sbhh[50 + j];

  for (int t = 0; t < cSEQ; ++t) {
    sx[nl][j] = xrow[t * 25 + j];
    __syncthreads();
    float gir = bihr, giz = bihz, gin = bihn;
    float ghr = bhhr, ghz = bhhz, ghn = bhhn;
    #pragma unroll
    for (int i = 0; i < 25; ++i) {
      float xv = sx[nl][i], hv = sh[nl][i];
      gir += sWih[j * 25 + i] * xv;
      giz += sWih[(25 + j) * 25 + i] * xv;
      gin += sWih[(50 + j) * 25 + i] * xv;
      ghr += sWhh[j * 25 + i] * hv;
      ghz += sWhh[(25 + j) * 25 + i] * hv;
      ghn += sWhh[(50 + j) * 25 + i] * hv;
    }
    float r = 1.0f / (1.0f + __expf(-(gir + ghr)));
    float z = 1.0f / (1.0f + __expf(-(giz + ghz)));
    float nn = tanhf(gin + r * ghn);
    float hnew = (1.0f - z) * nn + z * sh[nl][j];
    __syncthreads();          // everyone done reading old h
    sh[nl][j] = hnew;
    hrow[t * 25 + j] = hnew;
    __syncthreads();
  }
}

// ---------------- dense 625->32 + relu + BN stats ----------------
// block 256 = 32 outputs x 8 nodes. grid 20000/8 = 2500
__global__ void k_dense(const float* __restrict__ hs, const float* __restrict__ W,
                        const float* __restrict__ b, float* __restrict__ enc,
                        float* __restrict__ statsEnc) {
  __shared__ float sW[cENC * 625];      // 80 KB
  __shared__ float sstat[2 * cENC];
  int tid = threadIdx.x;
  for (int i = tid; i < cENC * 625; i += 256) sW[i] = W[i];
  if (tid < 2 * cENC) sstat[tid] = 0.0f;
  __syncthreads();

  int e  = tid & 31;
  int nl = tid >> 5;                    // 0..7
  int n  = blockIdx.x * 8 + nl;
  const float* hrow = hs + (size_t)n * 625;
  float acc = b[e];
  for (int f = 0; f < 625; ++f) acc += hrow[f] * sW[e * 625 + f];
  float v = fmaxf(acc, 0.0f);
  enc[(size_t)n * cENC + e] = v;

  // lanes L and L+32 share e: pair-reduce then bank-parallel LDS atomics
  float p = v + __shfl_down(v, 32);
  float q = v * v + __shfl_down(v * v, 32);
  if ((tid & 63) < 32) { atomicAdd(&sstat[e], p); atomicAdd(&sstat[cENC + e], q); }
  __syncthreads();
  if (tid < 2 * cENC) atomicAdd(&statsEnc[tid], sstat[tid]);
}

// ---------------- l2h gather: BN-enc affine + segment sum + count ----------------
__global__ void k_gather(const float* __restrict__ enc, const int* __restrict__ src,
                         const int* __restrict__ dst, const float* __restrict__ statsEnc,
                         const float* __restrict__ g, const float* __restrict__ bb,
                         float* __restrict__ agg, float* __restrict__ cnt) {
  __shared__ float ssc[cENC], ssh[cENC];
  int tid = threadIdx.x;
  if (tid < cENC) {
    float m = statsEnc[tid] * INV_NLOW;
    float var = statsEnc[cENC + tid] * INV_NLOW - m * m;
    float sc = g[tid] * rsqrtf(var + cEPS);
    ssc[tid] = sc;
    ssh[tid] = bb[tid] - m * sc;
  }
  __syncthreads();
  int eidx = blockIdx.x * 256 + tid;
  if (eidx >= cE_L2H) return;
  int s = src[eidx], t = dst[eidx];
  atomicAdd(&cnt[t], 1.0f);
  const float* er = enc + (size_t)s * cENC;
  float* ar = agg + (size_t)t * cENC;
  #pragma unroll
  for (int c = 0; c < cENC; ++c)
    atomicAdd(&ar[c], er[c] * ssc[c] + ssh[c]);
}

// ---------------- down-projection to high-res nodes + BN0 stats ----------------
__global__ void k_down(const float* __restrict__ agg, const float* __restrict__ cnt,
                       const float* __restrict__ z_std, const float* __restrict__ land,
                       const float* __restrict__ Wrel, const float* __restrict__ brel,
                       const float* __restrict__ Wroot,
                       float* __restrict__ x0, float* __restrict__ stats) {
  __shared__ float sstat[2 * cD];
  __shared__ float sWrel[cD * cENC], sWroot[cD * cHIGH_IN], sbrel[cD];
  int tid = threadIdx.x;
  if (tid < 2 * cD) sstat[tid] = 0.0f;
  for (int i = tid; i < cD * cENC; i += 256) sWrel[i] = Wrel[i];
  if (tid < cD * cHIGH_IN) sWroot[tid] = Wroot[tid];
  if (tid < cD) sbrel[tid] = brel[tid];
  __syncthreads();

  int n = blockIdx.x * 256 + tid;
  bool valid = n < cN_HIGH;
  float a[cENC], zz[cHIGH_IN];
  if (valid) {
    float inv = 1.0f / fmaxf(cnt[n], 1.0f);
    const float* ar = agg + (size_t)n * cENC;
    #pragma unroll
    for (int k = 0; k < cENC; ++k) a[k] = ar[k] * inv;
    #pragma unroll
    for (int k = 0; k < 6; ++k) zz[k] = z_std[(size_t)n * 6 + k];
    zz[6] = land[n];
  } else {
    #pragma unroll
    for (int k = 0; k < cENC; ++k) a[k] = 0.0f;
    #pragma unroll
    for (int k = 0; k < cHIGH_IN; ++k) zz[k] = 0.0f;
  }
  int lane = tid & 63;
  #pragma unroll
  for (int d = 0; d < cD; ++d) {
    float acc = sbrel[d];
    #pragma unroll
    for (int k = 0; k < cENC; ++k) acc += a[k] * sWrel[d * cENC + k];
    #pragma unroll
    for (int k = 0; k < cHIGH_IN; ++k) acc += zz[k] * sWroot[d * cHIGH_IN + k];
    if (valid) x0[(size_t)n * cD + d] = acc;
    float v = valid ? acc : 0.0f;
    float s1 = v, s2 = v * v;
    #pragma unroll
    for (int o = 32; o > 0; o >>= 1) { s1 += __shfl_down(s1, o); s2 += __shfl_down(s2, o); }
    if (lane == 0) { atomicAdd(&sstat[d], s1); atomicAdd(&sstat[cD + d], s2); }
  }
  __syncthreads();
  if (tid < 2 * cD) atomicAdd(&stats[tid], sstat[tid]);
}

// ---------------- GAT node transform: BN (+relu) + xl/xr; zero denom+msg ----------------
__global__ void k_transform(const float* __restrict__ xin, const float* __restrict__ stats,
                            const float* __restrict__ g, const float* __restrict__ b,
                            const float* __restrict__ Wl, const float* __restrict__ bl,
                            const float* __restrict__ Wr, const float* __restrict__ br,
                            int applyRelu,
                            float* __restrict__ xl, float* __restrict__ xr,
                            float* __restrict__ msgzero, float* __restrict__ denom) {
  __shared__ float ssc[cD], ssh[cD], sWl[cD * cD], sWr[cD * cD], sbl[cD], sbr[cD];
  int tid = threadIdx.x;
  if (tid < cD) {
    float m = stats[tid] * INV_NHIGH;
    float v = stats[cD + tid] * INV_NHIGH - m * m;
    float sc = g[tid] * rsqrtf(v + cEPS);
    ssc[tid] = sc;
    ssh[tid] = b[tid] - m * sc;
    sbl[tid] = bl[tid];
    sbr[tid] = br[tid];
  }
  if (tid < cD * cD) { sWl[tid] = Wl[tid]; sWr[tid] = Wr[tid]; }
  __syncthreads();

  int n = blockIdx.x * 256 + tid;
  if (n >= cN_HIGH) return;
  float act[cD];
  const float* xp = xin + (size_t)n * cD;
  #pragma unroll
  for (int d = 0; d < cD; ++d) {
    float v = xp[d] * ssc[d] + ssh[d];
    if (applyRelu) v = fmaxf(v, 0.0f);
    act[d] = v;
  }
  float* xlp = xl + (size_t)n * cD;
  float* xrp = xr + (size_t)n * cD;
  float* mz  = msgzero + (size_t)n * cD;
  #pragma unroll
  for (int d = 0; d < cD; ++d) {
    float al = sbl[d], ar = sbr[d];
    #pragma unroll
    for (int k = 0; k < cD; ++k) { al += act[k] * sWl[d * cD + k]; ar += act[k] * sWr[d * cD + k]; }
    xlp[d] = al;
    xrp[d] = ar;
    mz[d] = 0.0f;
  }
  denom[n] = 0.0f;
}

// ---------------- edge score + exp + denom (softmax shift-free) ----------------
__global__ void k_score(const float* __restrict__ xl, const float* __restrict__ xr,
                        const int* __restrict__ src, const int* __restrict__ dst,
                        const float* __restrict__ att,
                        float* __restrict__ ex, float* __restrict__ denom) {
  __shared__ float satt[cD];
  int tid = threadIdx.x;
  if (tid < cD) satt[tid] = att[tid];
  __syncthreads();
  int eidx = blockIdx.x * 256 + tid;
  if (eidx >= cE_TOT) return;
  int s, t;
  if (eidx < cE_HH) { s = src[eidx]; t = dst[eidx]; }
  else { s = eidx - cE_HH; t = s; }
  const float* lp = xl + (size_t)s * cD;
  const float* rp = xr + (size_t)t * cD;
  float e = 0.0f;
  #pragma unroll
  for (int d = 0; d < cD; ++d) {
    float v = lp[d] + rp[d];
    v = v > 0.0f ? v : cSLOPE * v;
    e += v * satt[d];
  }
  float xv = __expf(e);
  ex[eidx] = xv;
  atomicAdd(&denom[t], xv);
}

// ---------------- edge message scatter ----------------
__global__ void k_msg(const float* __restrict__ xl, const int* __restrict__ src,
                      const int* __restrict__ dst, const float* __restrict__ ex,
                      const float* __restrict__ denom, float* __restrict__ msg) {
  int eidx = blockIdx.x * 256 + threadIdx.x;
  if (eidx >= cE_TOT) return;
  int s, t;
  if (eidx < cE_HH) { s = src[eidx]; t = dst[eidx]; }
  else { s = eidx - cE_HH; t = s; }
  float alpha = ex[eidx] / denom[t];
  const float* lp = xl + (size_t)s * cD;
  float* mp = msg + (size_t)t * cD;
  #pragma unroll
  for (int d = 0; d < cD; ++d) atomicAdd(&mp[d], alpha * lp[d]);
}

// ---------------- finalize layer (mean + bias) + next BN stats ----------------
__global__ void k_finalize(float* __restrict__ msg, const float* __restrict__ cnt,
                           const float* __restrict__ bias, float* __restrict__ stats) {
  __shared__ float sstat[2 * cD];
  __shared__ float sbias[cD];
  int tid = threadIdx.x;
  if (tid < 2 * cD) sstat[tid] = 0.0f;
  if (tid < cD) sbias[tid] = bias[tid];
  __syncthreads();
  int n = blockIdx.x * 256 + tid;
  bool valid = n < cN_HIGH;
  float inv = 0.0f;
  float* mp = msg;
  if (valid) { inv = 1.0f / (cnt[n] + 1.0f); mp = msg + (size_t)n * cD; }
  int lane = tid & 63;
  #pragma unroll
  for (int d = 0; d < cD; ++d) {
    float v = 0.0f;
    if (valid) { v = mp[d] * inv + sbias[d]; mp[d] = v; }
    float s1 = v, s2 = v * v;
    #pragma unroll
    for (int o = 32; o > 0; o >>= 1) { s1 += __shfl_down(s1, o); s2 += __shfl_down(s2, o); }
    if (lane == 0) { atomicAdd(&sstat[d], s1); atomicAdd(&sstat[cD + d], s2); }
  }
  __syncthreads();
  if (tid < 2 * cD) atomicAdd(&stats[tid], sstat[tid]);
}

// ---------------- last layer: mean + bias + relu + predictor ----------------
__global__ void k_final(const float* __restrict__ msg, const float* __restrict__ cnt,
                        const float* __restrict__ bias, const float* __restrict__ pW,
                        const float* __restrict__ pb, float* __restrict__ out) {
  int n = blockIdx.x * 256 + threadIdx.x;
  if (n >= cN_HIGH) return;
  float inv = 1.0f / (cnt[n] + 1.0f);
  const float* mp = msg + (size_t)n * cD;
  float acc = pb[0];
  #pragma unroll
  for (int d = 0; d < cD; ++d) {
    float v = fmaxf(mp[d] * inv + bias[d], 0.0f);
    acc += v * pW[d];
  }
  out[n] = acc;
}

// ---------------- hh in-degree (excluding self loops) ----------------
__global__ void k_cnthh(const int* __restrict__ dst, float* __restrict__ cnt) {
  int e = blockIdx.x * 256 + threadIdx.x;
  if (e < cE_HH) atomicAdd(&cnt[dst[e]], 1.0f);
}

// ---------------- launch ----------------
extern "C" void kernel_launch(void* const* d_in, const int* in_sizes, int n_in,
                              void* d_out, int out_size, void* d_ws, size_t ws_size,
                              hipStream_t stream) {
  const float* x_low    = (const float*)d_in[0];
  const float* z_std    = (const float*)d_in[1];
  const float* land     = (const float*)d_in[2];
  const int*   l2h_src  = (const int*)d_in[3];
  const int*   l2h_dst  = (const int*)d_in[4];
  const int*   hh_src   = (const int*)d_in[5];
  const int*   hh_dst   = (const int*)d_in[6];
  const float* gWih     = (const float*)d_in[7];
  const float* gWhh     = (const float*)d_in[8];
  const float* gbih     = (const float*)d_in[9];
  const float* gbhh     = (const float*)d_in[10];
  const float* dW       = (const float*)d_in[11];
  const float* db       = (const float*)d_in[12];
  const float* bn_enc_g = (const float*)d_in[13];
  const float* bn_enc_b = (const float*)d_in[14];
  const float* Wrel     = (const float*)d_in[15];
  const float* brel     = (const float*)d_in[16];
  const float* Wroot    = (const float*)d_in[17];
  const float* gat_Wl   = (const float*)d_in[18];
  const float* gat_bl   = (const float*)d_in[19];
  const float* gat_Wr   = (const float*)d_in[20];
  const float* gat_br   = (const float*)d_in[21];
  const float* gat_att  = (const float*)d_in[22];
  const float* gat_bias = (const float*)d_in[23];
  const float* bn_g     = (const float*)d_in[24];
  const float* bn_b     = (const float*)d_in[25];
  const float* pred_W   = (const float*)d_in[26];
  const float* pred_b   = (const float*)d_in[27];

  float* ws = (float*)d_ws;
  float* hs      = ws + OFF_HS;
  float* enc     = ws + OFF_ENC;
  float* agg     = ws + OFF_AGG;
  float* cntl2h  = ws + OFF_CNTL;
  float* cnthh   = ws + OFF_CNTH;
  float* xA      = ws + OFF_XA;
  float* xB      = ws + OFF_XB;
  float* xl      = ws + OFF_XL;
  float* xr      = ws + OFF_XR;
  float* ex      = ws + OFF_EX;
  float* den     = ws + OFF_DEN;
  float* statsEnc = ws + OFF_STAT;          // 64 floats
  float* statsX   = ws + OFF_STAT + 64;     // 5 x 32 floats

  hipMemsetAsync(agg, 0, SZ_AGG * sizeof(float), stream);
  hipMemsetAsync(cntl2h, 0, cN_HIGH * sizeof(float), stream);
  hipMemsetAsync(cnthh, 0, cN_HIGH * sizeof(float), stream);
  hipMemsetAsync(statsEnc, 0, 256 * sizeof(float), stream);

  k_gru<<<cN_LOW / GRU_NODES, GRU_BLOCK, 0, stream>>>(x_low, gWih, gWhh, gbih, gbhh, hs);
  k_cnthh<<<(cE_HH + 255) / 256, 256, 0, stream>>>(hh_dst, cnthh);
  k_dense<<<cN_LOW / 8, 256, 0, stream>>>(hs, dW, db, enc, statsEnc);
  k_gather<<<(cE_L2H + 255) / 256, 256, 0, stream>>>(enc, l2h_src, l2h_dst, statsEnc,
                                                     bn_enc_g, bn_enc_b, agg, cntl2h);
  const int NODE_GRID = (cN_HIGH + 255) / 256;
  k_down<<<NODE_GRID, 256, 0, stream>>>(agg, cntl2h, z_std, land, Wrel, brel, Wroot,
                                        xA, statsX + 0);

  const int EDGE_GRID = (cE_TOT + 255) / 256;
  for (int i = 0; i < cNL; ++i) {
    float* xin  = (i & 1) ? xB : xA;
    float* xout = (i & 1) ? xA : xB;
    k_transform<<<NODE_GRID, 256, 0, stream>>>(xin, statsX + 32 * i,
                                               bn_g + 16 * i, bn_b + 16 * i,
                                               gat_Wl + 256 * i, gat_bl + 16 * i,
                                               gat_Wr + 256 * i, gat_br + 16 * i,
                                               (i > 0) ? 1 : 0, xl, xr, xout, den);
    k_score<<<EDGE_GRID, 256, 0, stream>>>(xl, xr, hh_src, hh_dst, gat_att + 16 * i, ex, den);
    k_msg<<<EDGE_GRID, 256, 0, stream>>>(xl, hh_src, hh_dst, ex, den, xout);
    if (i < cNL - 1) {
      k_finalize<<<NODE_GRID, 256, 0, stream>>>(xout, cnthh, gat_bias + 16 * i, statsX + 32 * (i + 1));
    } else {
      k_final<<<NODE_GRID, 256, 0, stream>>>(xout, cnthh, gat_bias + 16 * i, pred_W, pred_b,
                                             (float*)d_out);
    }
  }
}

// Round 2
// 2189.283 us; speedup vs baseline: 4.1287x; 4.1287x over previous
//
#include <hip/hip_runtime.h>
#include <hip/hip_bf16.h>
#include <cstddef>

// ---------------- problem constants ----------------
constexpr int cN_LOW  = 20000;
constexpr int cN_HIGH = 150000;
constexpr int cSEQ = 25;
constexpr int cHIN = 25;
constexpr int cHHID = 25;
constexpr int cENC = 32;
constexpr int cHIGH_IN = 7;
constexpr int cD = 16;
constexpr int cNL = 5;
constexpr int cE_L2H = 1350000;
constexpr int cE_HH = 1200000;
constexpr float cEPS = 1e-5f;
constexpr float cSLOPE = 0.2f;
constexpr float INV_NLOW  = 1.0f / (float)cN_LOW;
constexpr float INV_NHIGH = 1.0f / (float)cN_HIGH;

// ---------------- workspace layout (4-byte element offsets) ----------------
// agg aliases hs (hs is dead once k_dense finishes; gather runs after).
constexpr size_t OFF_HS   = 0;                                   // [N_LOW*625] fp32
constexpr size_t SZ_HS    = (size_t)cN_LOW * 625;
constexpr size_t OFF_AGG  = 0;                                   // [N_HIGH*32] fp32 (alias)
constexpr size_t OFF_ENC  = OFF_HS + SZ_HS;                      // [N_LOW*32]
constexpr size_t SZ_ENC   = (size_t)cN_LOW * cENC;
constexpr size_t OFF_XA   = OFF_ENC + SZ_ENC;
constexpr size_t OFF_XB   = OFF_XA + (size_t)cN_HIGH * cD;
constexpr size_t OFF_XL   = OFF_XB + (size_t)cN_HIGH * cD;
constexpr size_t OFF_XR   = OFF_XL + (size_t)cN_HIGH * cD;
constexpr size_t OFF_STAT = OFF_XR + (size_t)cN_HIGH * cD;       // [256]
constexpr size_t OFF_RPH  = OFF_STAT + 256;                      // rowptr_hh [N_HIGH+1] int
constexpr size_t OFF_SRH  = OFF_RPH + cN_HIGH + 1;               // src_hh sorted [E_HH] int
constexpr size_t OFF_RPL  = OFF_SRH + cE_HH;                     // rowptr_l2h [N_HIGH+1] int
constexpr size_t OFF_SRL  = OFF_RPL + cN_HIGH + 1;               // src_l2h sorted [E_L2H] int
constexpr size_t OFF_CUR  = OFF_SRL + cE_L2H;                    // cursor/deg [N_HIGH] int
// total ~25.74M elements ~103 MB

// ---------------- GRU kernel ----------------
constexpr int GRU_NODES = 10;
constexpr int GRU_BLOCK = GRU_NODES * cHHID;   // 250

__global__ void k_gru(const float* __restrict__ x_low,
                      const float* __restrict__ Wih, const float* __restrict__ Whh,
                      const float* __restrict__ bih, const float* __restrict__ bhh,
                      float* __restrict__ hs) {
  __shared__ float sWih[75 * 25];
  __shared__ float sWhh[75 * 25];
  __shared__ float sbih[75], sbhh[75];
  __shared__ float sx[GRU_NODES][cHIN];
  __shared__ float sh[GRU_NODES][cHHID];

  int tid = threadIdx.x;
  for (int i = tid; i < 75 * 25; i += GRU_BLOCK) { sWih[i] = Wih[i]; sWhh[i] = Whh[i]; }
  for (int i = tid; i < 75; i += GRU_BLOCK) { sbih[i] = bih[i]; sbhh[i] = bhh[i]; }

  int nl = tid / cHHID;
  int j  = tid % cHHID;
  int n  = blockIdx.x * GRU_NODES + nl;
  sh[nl][j] = 0.0f;
  __syncthreads();

  const float* xrow = x_low + (size_t)n * 625;
  float* hrow = hs + (size_t)n * 625;
  float bihr = sbih[j], bihz = sbih[25 + j], bihn = sbih[50 + j];
  float bhhr = sbhh[j], bhhz = sbhh[25 + j], bhhn = sbhh[50 + j];

  for (int t = 0; t < cSEQ; ++t) {
    sx[nl][j] = xrow[t * 25 + j];
    __syncthreads();
    float gir = bihr, giz = bihz, gin = bihn;
    float ghr = bhhr, ghz = bhhz, ghn = bhhn;
    #pragma unroll
    for (int i = 0; i < 25; ++i) {
      float xv = sx[nl][i], hv = sh[nl][i];
      gir += sWih[j * 25 + i] * xv;
      giz += sWih[(25 + j) * 25 + i] * xv;
      gin += sWih[(50 + j) * 25 + i] * xv;
      ghr += sWhh[j * 25 + i] * hv;
      ghz += sWhh[(25 + j) * 25 + i] * hv;
      ghn += sWhh[(50 + j) * 25 + i] * hv;
    }
    float r = 1.0f / (1.0f + __expf(-(gir + ghr)));
    float z = 1.0f / (1.0f + __expf(-(giz + ghz)));
    float nn = tanhf(gin + r * ghn);
    float hnew = (1.0f - z) * nn + z * sh[nl][j];
    __syncthreads();
    sh[nl][j] = hnew;
    hrow[t * 25 + j] = hnew;
    __syncthreads();
  }
}

// ---------------- dense 625->32 + relu + BN stats ----------------
__global__ void k_dense(const float* __restrict__ hs, const float* __restrict__ W,
                        const float* __restrict__ b, float* __restrict__ enc,
                        float* __restrict__ statsEnc) {
  __shared__ float sW[cENC * 625];      // 80 KB
  __shared__ float sstat[2 * cENC];
  int tid = threadIdx.x;
  for (int i = tid; i < cENC * 625; i += 256) sW[i] = W[i];
  if (tid < 2 * cENC) sstat[tid] = 0.0f;
  __syncthreads();

  int e  = tid & 31;
  int nl = tid >> 5;
  int n  = blockIdx.x * 8 + nl;
  const float* hrow = hs + (size_t)n * 625;
  float acc = b[e];
  for (int f = 0; f < 625; ++f) acc += hrow[f] * sW[e * 625 + f];
  float v = fmaxf(acc, 0.0f);
  enc[(size_t)n * cENC + e] = v;

  float p = v + __shfl_down(v, 32);
  float q = v * v + __shfl_down(v * v, 32);
  if ((tid & 63) < 32) { atomicAdd(&sstat[e], p); atomicAdd(&sstat[cENC + e], q); }
  __syncthreads();
  if (tid < 2 * cENC) atomicAdd(&statsEnc[tid], sstat[tid]);
}

// ---------------- CSR build: histogram / scan / scatter ----------------
__global__ void k_hist(const int* __restrict__ dst, int nE, int* __restrict__ cnt) {
  int e = blockIdx.x * 256 + threadIdx.x;
  if (e < nE) atomicAdd(&cnt[dst[e]], 1);
}

constexpr int SCAN_T = 1024;
// deg_cursor holds per-node degree on entry; on exit holds row start (cursor init).
__global__ void k_scan(int* deg_cursor, int n, int* rowptr) {
  __shared__ int ssum[SCAN_T];
  int tid = threadIdx.x;
  int chunk = (n + SCAN_T - 1) / SCAN_T;
  int lo = tid * chunk;
  int hi = lo + chunk; if (hi > n) hi = n;
  if (lo > n) lo = n;
  int s = 0;
  for (int i = lo; i < hi; ++i) s += deg_cursor[i];
  ssum[tid] = s;
  __syncthreads();
  for (int off = 1; off < SCAN_T; off <<= 1) {
    int v = (tid >= off) ? ssum[tid - off] : 0;
    __syncthreads();
    ssum[tid] += v;
    __syncthreads();
  }
  int run = ssum[tid] - s;            // exclusive prefix for this thread's chunk
  for (int i = lo; i < hi; ++i) {
    int c = deg_cursor[i];
    rowptr[i] = run;
    deg_cursor[i] = run;
    run += c;
  }
  if (tid == SCAN_T - 1) rowptr[n] = run;
}

__global__ void k_scatter(const int* __restrict__ src, const int* __restrict__ dst, int nE,
                          int* __restrict__ cursor, int* __restrict__ out) {
  int e = blockIdx.x * 256 + threadIdx.x;
  if (e < nE) {
    int pos = atomicAdd(&cursor[dst[e]], 1);
    out[pos] = src[e];
  }
}

// ---------------- l2h gather via CSR: BN-enc affine + mean ----------------
// block 256 = 8 nodes x 32 channels
__global__ void k_gather_csr(const float* __restrict__ enc, const int* __restrict__ rowptr,
                             const int* __restrict__ srcs, const float* __restrict__ statsEnc,
                             const float* __restrict__ g, const float* __restrict__ bb,
                             float* __restrict__ agg) {
  __shared__ float ssc[cENC], ssh[cENC];
  int tid = threadIdx.x;
  if (tid < cENC) {
    float m = statsEnc[tid] * INV_NLOW;
    float var = statsEnc[cENC + tid] * INV_NLOW - m * m;
    float sc = g[tid] * rsqrtf(var + cEPS);
    ssc[tid] = sc;
    ssh[tid] = bb[tid] - m * sc;
  }
  __syncthreads();
  int c = tid & 31;
  int n = blockIdx.x * 8 + (tid >> 5);
  int lo = rowptr[n], hi = rowptr[n + 1];
  float sum = 0.0f;
  for (int i = lo; i < hi; ++i) {
    int s = srcs[i];
    sum += enc[(size_t)s * cENC + c];
  }
  float deg = (float)(hi - lo);
  agg[(size_t)n * cENC + c] = (ssc[c] * sum + deg * ssh[c]) / fmaxf(deg, 1.0f);
}

// ---------------- down-projection (mean already applied) + BN0 stats ----------------
__global__ void k_down(const float* __restrict__ agg,
                       const float* __restrict__ z_std, const float* __restrict__ land,
                       const float* __restrict__ Wrel, const float* __restrict__ brel,
                       const float* __restrict__ Wroot,
                       float* __restrict__ x0, float* __restrict__ stats) {
  __shared__ float sstat[2 * cD];
  __shared__ float sWrel[cD * cENC], sWroot[cD * cHIGH_IN], sbrel[cD];
  int tid = threadIdx.x;
  if (tid < 2 * cD) sstat[tid] = 0.0f;
  for (int i = tid; i < cD * cENC; i += 256) sWrel[i] = Wrel[i];
  if (tid < cD * cHIGH_IN) sWroot[tid] = Wroot[tid];
  if (tid < cD) sbrel[tid] = brel[tid];
  __syncthreads();

  int n = blockIdx.x * 256 + tid;
  bool valid = n < cN_HIGH;
  float a[cENC], zz[cHIGH_IN];
  if (valid) {
    const float* ar = agg + (size_t)n * cENC;
    #pragma unroll
    for (int k = 0; k < cENC; ++k) a[k] = ar[k];
    #pragma unroll
    for (int k = 0; k < 6; ++k) zz[k] = z_std[(size_t)n * 6 + k];
    zz[6] = land[n];
  } else {
    #pragma unroll
    for (int k = 0; k < cENC; ++k) a[k] = 0.0f;
    #pragma unroll
    for (int k = 0; k < cHIGH_IN; ++k) zz[k] = 0.0f;
  }
  int lane = tid & 63;
  #pragma unroll
  for (int d = 0; d < cD; ++d) {
    float acc = sbrel[d];
    #pragma unroll
    for (int k = 0; k < cENC; ++k) acc += a[k] * sWrel[d * cENC + k];
    #pragma unroll
    for (int k = 0; k < cHIGH_IN; ++k) acc += zz[k] * sWroot[d * cHIGH_IN + k];
    if (valid) x0[(size_t)n * cD + d] = acc;
    float v = valid ? acc : 0.0f;
    float s1 = v, s2 = v * v;
    #pragma unroll
    for (int o = 32; o > 0; o >>= 1) { s1 += __shfl_down(s1, o); s2 += __shfl_down(s2, o); }
    if (lane == 0) { atomicAdd(&sstat[d], s1); atomicAdd(&sstat[cD + d], s2); }
  }
  __syncthreads();
  if (tid < 2 * cD) atomicAdd(&stats[tid], sstat[tid]);
}

// ---------------- GAT node transform: BN (+relu) + xl/xr ----------------
__global__ void k_transform(const float* __restrict__ xin, const float* __restrict__ stats,
                            const float* __restrict__ g, const float* __restrict__ b,
                            const float* __restrict__ Wl, const float* __restrict__ bl,
                            const float* __restrict__ Wr, const float* __restrict__ br,
                            int applyRelu,
                            float* __restrict__ xl, float* __restrict__ xr) {
  __shared__ float ssc[cD], ssh[cD], sWl[cD * cD], sWr[cD * cD], sbl[cD], sbr[cD];
  int tid = threadIdx.x;
  if (tid < cD) {
    float m = stats[tid] * INV_NHIGH;
    float v = stats[cD + tid] * INV_NHIGH - m * m;
    float sc = g[tid] * rsqrtf(v + cEPS);
    ssc[tid] = sc;
    ssh[tid] = b[tid] - m * sc;
    sbl[tid] = bl[tid];
    sbr[tid] = br[tid];
  }
  if (tid < cD * cD) { sWl[tid] = Wl[tid]; sWr[tid] = Wr[tid]; }
  __syncthreads();

  int n = blockIdx.x * 256 + tid;
  if (n >= cN_HIGH) return;
  float act[cD];
  const float* xp = xin + (size_t)n * cD;
  #pragma unroll
  for (int d = 0; d < cD; ++d) {
    float v = xp[d] * ssc[d] + ssh[d];
    if (applyRelu) v = fmaxf(v, 0.0f);
    act[d] = v;
  }
  float* xlp = xl + (size_t)n * cD;
  float* xrp = xr + (size_t)n * cD;
  #pragma unroll
  for (int d = 0; d < cD; ++d) {
    float al = sbl[d], ar = sbr[d];
    #pragma unroll
    for (int k = 0; k < cD; ++k) { al += act[k] * sWl[d * cD + k]; ar += act[k] * sWr[d * cD + k]; }
    xlp[d] = al;
    xrp[d] = ar;
  }
}

// ---------------- fused GAT edge pass via CSR ----------------
// softmax w/o max-shift: out = (sum_e exp(e) xl[s_e]) / (sum_e exp(e)) / cnt + bias
// block 256 = 16 nodes x 16 channels; 150000/16 = 9375 blocks exactly.
template<int FINAL>
__global__ void k_edge(const float* __restrict__ xl, const float* __restrict__ xr,
                       const int* __restrict__ rowptr, const int* __restrict__ srcs,
                       const float* __restrict__ att, const float* __restrict__ bias,
                       const float* __restrict__ pW, const float* __restrict__ pb,
                       float* __restrict__ xout, float* __restrict__ stats,
                       float* __restrict__ out) {
  __shared__ float satt[cD], sbias[cD];
  __shared__ float sstat[2 * cD];
  int tid = threadIdx.x;
  if (tid < cD) { satt[tid] = att[tid]; sbias[tid] = bias[tid]; }
  if (!FINAL && tid < 2 * cD) sstat[tid] = 0.0f;
  __syncthreads();

  int d = tid & 15;
  int n = blockIdx.x * 16 + (tid >> 4);
  float a_d = satt[d];
  float xr_d = xr[(size_t)n * cD + d];
  float xl_self = xl[(size_t)n * cD + d];

  // self loop
  float v = xl_self + xr_d;
  v = v > 0.0f ? v : cSLOPE * v;
  float p = v * a_d;
  p += __shfl_xor(p, 1); p += __shfl_xor(p, 2); p += __shfl_xor(p, 4); p += __shfl_xor(p, 8);
  float ex = __expf(p);
  float denom = ex;
  float num = ex * xl_self;

  int lo = rowptr[n], hi = rowptr[n + 1];
  for (int i = lo; i < hi; ++i) {
    int s = srcs[i];
    float xls = xl[(size_t)s * cD + d];
    float w = xls + xr_d;
    w = w > 0.0f ? w : cSLOPE * w;
    float q = w * a_d;
    q += __shfl_xor(q, 1); q += __shfl_xor(q, 2); q += __shfl_xor(q, 4); q += __shfl_xor(q, 8);
    float e2 = __expf(q);
    denom += e2;
    num += e2 * xls;
  }
  float cnt = (float)(hi - lo + 1);
  float res = num / denom / cnt + sbias[d];

  if (FINAL) {
    float t = fmaxf(res, 0.0f) * pW[d];
    t += __shfl_xor(t, 1); t += __shfl_xor(t, 2); t += __shfl_xor(t, 4); t += __shfl_xor(t, 8);
    if (d == 0) out[n] = t + pb[0];
  } else {
    xout[(size_t)n * cD + d] = res;
    float s1 = res, s2 = res * res;
    s1 += __shfl_xor(s1, 16); s2 += __shfl_xor(s2, 16);
    s1 += __shfl_xor(s1, 32); s2 += __shfl_xor(s2, 32);
    if ((tid & 63) < 16) { atomicAdd(&sstat[d], s1); atomicAdd(&sstat[cD + d], s2); }
    __syncthreads();
    if (tid < 2 * cD) atomicAdd(&stats[tid], sstat[tid]);
  }
}

// ---------------- launch ----------------
extern "C" void kernel_launch(void* const* d_in, const int* in_sizes, int n_in,
                              void* d_out, int out_size, void* d_ws, size_t ws_size,
                              hipStream_t stream) {
  const float* x_low    = (const float*)d_in[0];
  const float* z_std    = (const float*)d_in[1];
  const float* land     = (const float*)d_in[2];
  const int*   l2h_src  = (const int*)d_in[3];
  const int*   l2h_dst  = (const int*)d_in[4];
  const int*   hh_src   = (const int*)d_in[5];
  const int*   hh_dst   = (const int*)d_in[6];
  const float* gWih     = (const float*)d_in[7];
  const float* gWhh     = (const float*)d_in[8];
  const float* gbih     = (const float*)d_in[9];
  const float* gbhh     = (const float*)d_in[10];
  const float* dW       = (const float*)d_in[11];
  const float* db       = (const float*)d_in[12];
  const float* bn_enc_g = (const float*)d_in[13];
  const float* bn_enc_b = (const float*)d_in[14];
  const float* Wrel     = (const float*)d_in[15];
  const float* brel     = (const float*)d_in[16];
  const float* Wroot    = (const float*)d_in[17];
  const float* gat_Wl   = (const float*)d_in[18];
  const float* gat_bl   = (const float*)d_in[19];
  const float* gat_Wr   = (const float*)d_in[20];
  const float* gat_br   = (const float*)d_in[21];
  const float* gat_att  = (const float*)d_in[22];
  const float* gat_bias = (const float*)d_in[23];
  const float* bn_g     = (const float*)d_in[24];
  const float* bn_b     = (const float*)d_in[25];
  const float* pred_W   = (const float*)d_in[26];
  const float* pred_b   = (const float*)d_in[27];

  float* ws = (float*)d_ws;
  float* hs   = ws + OFF_HS;
  float* agg  = ws + OFF_AGG;
  float* enc  = ws + OFF_ENC;
  float* xA   = ws + OFF_XA;
  float* xB   = ws + OFF_XB;
  float* xl   = ws + OFF_XL;
  float* xr   = ws + OFF_XR;
  float* statsEnc = ws + OFF_STAT;          // 64 floats
  float* statsX   = ws + OFF_STAT + 64;     // 5 x 32 floats
  int* rp_hh  = (int*)(ws + OFF_RPH);
  int* src_hh = (int*)(ws + OFF_SRH);
  int* rp_l2h = (int*)(ws + OFF_RPL);
  int* src_l2h= (int*)(ws + OFF_SRL);
  int* cursor = (int*)(ws + OFF_CUR);

  hipMemsetAsync(statsEnc, 0, 256 * sizeof(float), stream);

  // --- CSR build: hh ---
  hipMemsetAsync(cursor, 0, cN_HIGH * sizeof(int), stream);
  k_hist<<<(cE_HH + 255) / 256, 256, 0, stream>>>(hh_dst, cE_HH, cursor);
  k_scan<<<1, SCAN_T, 0, stream>>>(cursor, cN_HIGH, rp_hh);
  k_scatter<<<(cE_HH + 255) / 256, 256, 0, stream>>>(hh_src, hh_dst, cE_HH, cursor, src_hh);
  // --- CSR build: l2h ---
  hipMemsetAsync(cursor, 0, cN_HIGH * sizeof(int), stream);
  k_hist<<<(cE_L2H + 255) / 256, 256, 0, stream>>>(l2h_dst, cE_L2H, cursor);
  k_scan<<<1, SCAN_T, 0, stream>>>(cursor, cN_HIGH, rp_l2h);
  k_scatter<<<(cE_L2H + 255) / 256, 256, 0, stream>>>(l2h_src, l2h_dst, cE_L2H, cursor, src_l2h);

  // --- encoder ---
  k_gru<<<cN_LOW / GRU_NODES, GRU_BLOCK, 0, stream>>>(x_low, gWih, gWhh, gbih, gbhh, hs);
  k_dense<<<cN_LOW / 8, 256, 0, stream>>>(hs, dW, db, enc, statsEnc);
  k_gather_csr<<<cN_HIGH / 8, 256, 0, stream>>>(enc, rp_l2h, src_l2h, statsEnc,
                                                bn_enc_g, bn_enc_b, agg);
  const int NODE_GRID = (cN_HIGH + 255) / 256;
  k_down<<<NODE_GRID, 256, 0, stream>>>(agg, z_std, land, Wrel, brel, Wroot, xA, statsX);

  // --- 5 GATv2 layers ---
  for (int i = 0; i < cNL; ++i) {
    float* xin  = (i & 1) ? xB : xA;
    float* xout = (i & 1) ? xA : xB;
    k_transform<<<NODE_GRID, 256, 0, stream>>>(xin, statsX + 32 * i,
                                               bn_g + 16 * i, bn_b + 16 * i,
                                               gat_Wl + 256 * i, gat_bl + 16 * i,
                                               gat_Wr + 256 * i, gat_br + 16 * i,
                                               (i > 0) ? 1 : 0, xl, xr);
    if (i < cNL - 1) {
      k_edge<0><<<cN_HIGH / 16, 256, 0, stream>>>(xl, xr, rp_hh, src_hh,
                                                  gat_att + 16 * i, gat_bias + 16 * i,
                                                  nullptr, nullptr,
                                                  xout, statsX + 32 * (i + 1), nullptr);
    } else {
      k_edge<1><<<cN_HIGH / 16, 256, 0, stream>>>(xl, xr, rp_hh, src_hh,
                                                  gat_att + 16 * i, gat_bias + 16 * i,
                                                  pred_W, pred_b,
                                                  nullptr, nullptr, (float*)d_out);
    }
  }
}

// Round 3
// 1542.020 us; speedup vs baseline: 5.8617x; 1.4198x over previous
//
#include <hip/hip_runtime.h>
#include <hip/hip_bf16.h>
#include <cstddef>

// ---------------- problem constants ----------------
constexpr int cN_LOW  = 20000;
constexpr int cN_HIGH = 150000;
constexpr int cSEQ = 25;
constexpr int cHIN = 25;
constexpr int cHHID = 25;
constexpr int cENC = 32;
constexpr int cHIGH_IN = 7;
constexpr int cD = 16;
constexpr int cNL = 5;
constexpr int cE_L2H = 1350000;
constexpr int cE_HH = 1200000;
constexpr float cEPS = 1e-5f;
constexpr float cSLOPE = 0.2f;
constexpr float INV_NLOW  = 1.0f / (float)cN_LOW;
constexpr float INV_NHIGH = 1.0f / (float)cN_HIGH;

// scan geometry
constexpr int SC_ELEM = 1024;                                  // elems per scan block
constexpr int SC_NB   = (cN_HIGH + SC_ELEM - 1) / SC_ELEM;     // 147
static_assert(SC_NB <= 256, "top scan assumes <=256 partials");

// ---------------- workspace layout (4-byte element offsets) ----------------
// agg aliases hs (hs dead after k_dense).
constexpr size_t OFF_HS   = 0;                                   // [N_LOW*625]
constexpr size_t SZ_HS    = (size_t)cN_LOW * 625;
constexpr size_t OFF_AGG  = 0;                                   // alias
constexpr size_t OFF_ENC  = OFF_HS + SZ_HS;                      // [N_LOW*32]
constexpr size_t SZ_ENC   = (size_t)cN_LOW * cENC;
constexpr size_t OFF_XA   = OFF_ENC + SZ_ENC;
constexpr size_t OFF_XB   = OFF_XA + (size_t)cN_HIGH * cD;
constexpr size_t OFF_XL   = OFF_XB + (size_t)cN_HIGH * cD;
constexpr size_t OFF_XR   = OFF_XL + (size_t)cN_HIGH * cD;
constexpr size_t OFF_STAT = OFF_XR + (size_t)cN_HIGH * cD;       // [256]
constexpr size_t OFF_RPH  = OFF_STAT + 256;                      // rowptr_hh [N_HIGH+4] (padded for int4 align)
constexpr size_t OFF_SRH  = OFF_RPH + cN_HIGH + 4;               // src_hh sorted [E_HH]
constexpr size_t OFF_RPL  = OFF_SRH + cE_HH;                     // rowptr_l2h [N_HIGH+4]
constexpr size_t OFF_SRL  = OFF_RPL + cN_HIGH + 4;               // src_l2h sorted [E_L2H]
constexpr size_t OFF_CUR  = OFF_SRL + cE_L2H;                    // deg/cursor [N_HIGH]
constexpr size_t OFF_PART = OFF_CUR + cN_HIGH;                   // partials [256]

// ---------------- GRU kernel ----------------
constexpr int GRU_NODES = 10;
constexpr int GRU_BLOCK = GRU_NODES * cHHID;   // 250

__global__ void k_gru(const float* __restrict__ x_low,
                      const float* __restrict__ Wih, const float* __restrict__ Whh,
                      const float* __restrict__ bih, const float* __restrict__ bhh,
                      float* __restrict__ hs) {
  __shared__ float sWih[75 * 25];
  __shared__ float sWhh[75 * 25];
  __shared__ float sbih[75], sbhh[75];
  __shared__ float sx[GRU_NODES][cHIN];
  __shared__ float sh[GRU_NODES][cHHID];

  int tid = threadIdx.x;
  for (int i = tid; i < 75 * 25; i += GRU_BLOCK) { sWih[i] = Wih[i]; sWhh[i] = Whh[i]; }
  for (int i = tid; i < 75; i += GRU_BLOCK) { sbih[i] = bih[i]; sbhh[i] = bhh[i]; }

  int nl = tid / cHHID;
  int j  = tid % cHHID;
  int n  = blockIdx.x * GRU_NODES + nl;
  sh[nl][j] = 0.0f;
  __syncthreads();

  const float* xrow = x_low + (size_t)n * 625;
  float* hrow = hs + (size_t)n * 625;
  float bihr = sbih[j], bihz = sbih[25 + j], bihn = sbih[50 + j];
  float bhhr = sbhh[j], bhhz = sbhh[25 + j], bhhn = sbhh[50 + j];

  for (int t = 0; t < cSEQ; ++t) {
    sx[nl][j] = xrow[t * 25 + j];
    __syncthreads();
    float gir = bihr, giz = bihz, gin = bihn;
    float ghr = bhhr, ghz = bhhz, ghn = bhhn;
    #pragma unroll
    for (int i = 0; i < 25; ++i) {
      float xv = sx[nl][i], hv = sh[nl][i];
      gir += sWih[j * 25 + i] * xv;
      giz += sWih[(25 + j) * 25 + i] * xv;
      gin += sWih[(50 + j) * 25 + i] * xv;
      ghr += sWhh[j * 25 + i] * hv;
      ghz += sWhh[(25 + j) * 25 + i] * hv;
      ghn += sWhh[(50 + j) * 25 + i] * hv;
    }
    float r = 1.0f / (1.0f + __expf(-(gir + ghr)));
    float z = 1.0f / (1.0f + __expf(-(giz + ghz)));
    float nn = tanhf(gin + r * ghn);
    float hnew = (1.0f - z) * nn + z * sh[nl][j];
    __syncthreads();
    sh[nl][j] = hnew;
    hrow[t * 25 + j] = hnew;
    __syncthreads();
  }
}

// ---------------- dense 625->32 + relu + BN stats ----------------
__global__ void k_dense(const float* __restrict__ hs, const float* __restrict__ W,
                        const float* __restrict__ b, float* __restrict__ enc,
                        float* __restrict__ statsEnc) {
  __shared__ float sW[cENC * 625];      // 80 KB
  __shared__ float sstat[2 * cENC];
  int tid = threadIdx.x;
  for (int i = tid; i < cENC * 625; i += 256) sW[i] = W[i];
  if (tid < 2 * cENC) sstat[tid] = 0.0f;
  __syncthreads();

  int e  = tid & 31;
  int nl = tid >> 5;
  int n  = blockIdx.x * 8 + nl;
  const float* hrow = hs + (size_t)n * 625;
  float acc = b[e];
  for (int f = 0; f < 625; ++f) acc += hrow[f] * sW[e * 625 + f];
  float v = fmaxf(acc, 0.0f);
  enc[(size_t)n * cENC + e] = v;

  float p = v + __shfl_down(v, 32);
  float q = v * v + __shfl_down(v * v, 32);
  if ((tid & 63) < 32) { atomicAdd(&sstat[e], p); atomicAdd(&sstat[cENC + e], q); }
  __syncthreads();
  if (tid < 2 * cENC) atomicAdd(&statsEnc[tid], sstat[tid]);
}

// ---------------- CSR build ----------------
__global__ void k_hist(const int* __restrict__ dst, int nE, int* __restrict__ cnt) {
  int e = blockIdx.x * 256 + threadIdx.x;
  if (e < nE) atomicAdd(&cnt[dst[e]], 1);
}

// block-local exclusive scan of 1024 elems (4/thread, int4), emit block total
__global__ void k_scan_local(const int* __restrict__ deg, int n,
                             int* __restrict__ out, int* __restrict__ partial) {
  int tid = threadIdx.x;
  int base = blockIdx.x * SC_ELEM + tid * 4;
  int4 v = make_int4(0, 0, 0, 0);
  if (base + 3 < n) v = *(const int4*)(deg + base);
  else { int* pv = (int*)&v; for (int k = 0; k < 4; ++k) if (base + k < n) pv[k] = deg[base + k]; }
  int tsum = v.x + v.y + v.z + v.w;
  int lane = tid & 63;
  int inc = tsum;
  #pragma unroll
  for (int o = 1; o < 64; o <<= 1) { int t = __shfl_up(inc, o); if (lane >= o) inc += t; }
  __shared__ int wtot[4];
  if (lane == 63) wtot[tid >> 6] = inc;
  __syncthreads();
  int w = tid >> 6, wbase = 0;
  #pragma unroll
  for (int k = 0; k < 3; ++k) if (k < w) wbase += wtot[k];
  int ebase = wbase + inc - tsum;
  int4 o4;
  o4.x = ebase; o4.y = ebase + v.x; o4.z = o4.y + v.y; o4.w = o4.z + v.z;
  if (base + 3 < n) *(int4*)(out + base) = o4;
  else { int* po = (int*)&o4; for (int k = 0; k < 4; ++k) if (base + k < n) out[base + k] = po[k]; }
  if (tid == 255) partial[blockIdx.x] = wbase + inc;   // block total
}

// single-block scan of <=256 partials -> exclusive offsets; writes grand total
__global__ void k_scan_top(int* __restrict__ partial, int nb, int* __restrict__ total_out) {
  __shared__ int sd[256];
  int tid = threadIdx.x;
  int v = (tid < nb) ? partial[tid] : 0;
  sd[tid] = v;
  __syncthreads();
  for (int off = 1; off < 256; off <<= 1) {
    int t = (tid >= off) ? sd[tid - off] : 0;
    __syncthreads();
    sd[tid] += t;
    __syncthreads();
  }
  if (tid < nb) partial[tid] = sd[tid] - v;
  if (tid == 255) *total_out = sd[255];
}

// add block offsets; also init cursor = rowptr
__global__ void k_scan_add(int* __restrict__ rowptr, const int* __restrict__ partial,
                           int n, int* __restrict__ cursor) {
  int base = blockIdx.x * SC_ELEM + threadIdx.x * 4;
  int add = partial[blockIdx.x];
  if (base + 3 < n) {
    int4 v = *(int4*)(rowptr + base);
    v.x += add; v.y += add; v.z += add; v.w += add;
    *(int4*)(rowptr + base) = v;
    *(int4*)(cursor + base) = v;
  } else {
    for (int k = 0; k < 4; ++k)
      if (base + k < n) { int t = rowptr[base + k] + add; rowptr[base + k] = t; cursor[base + k] = t; }
  }
}

__global__ void k_scatter(const int* __restrict__ src, const int* __restrict__ dst, int nE,
                          int* __restrict__ cursor, int* __restrict__ out) {
  int e = blockIdx.x * 256 + threadIdx.x;
  if (e < nE) {
    int pos = atomicAdd(&cursor[dst[e]], 1);
    out[pos] = src[e];
  }
}

// ---------------- l2h gather via CSR: BN-enc affine + mean ----------------
__global__ void k_gather_csr(const float* __restrict__ enc, const int* __restrict__ rowptr,
                             const int* __restrict__ srcs, const float* __restrict__ statsEnc,
                             const float* __restrict__ g, const float* __restrict__ bb,
                             float* __restrict__ agg) {
  __shared__ float ssc[cENC], ssh[cENC];
  int tid = threadIdx.x;
  if (tid < cENC) {
    float m = statsEnc[tid] * INV_NLOW;
    float var = statsEnc[cENC + tid] * INV_NLOW - m * m;
    float sc = g[tid] * rsqrtf(var + cEPS);
    ssc[tid] = sc;
    ssh[tid] = bb[tid] - m * sc;
  }
  __syncthreads();
  int c = tid & 31;
  int n = blockIdx.x * 8 + (tid >> 5);
  int lo = rowptr[n], hi = rowptr[n + 1];
  float sum = 0.0f;
  for (int i = lo; i < hi; ++i) {
    int s = srcs[i];
    sum += enc[(size_t)s * cENC + c];
  }
  float deg = (float)(hi - lo);
  agg[(size_t)n * cENC + c] = (ssc[c] * sum + deg * ssh[c]) / fmaxf(deg, 1.0f);
}

// ---------------- down-projection + BN0 stats ----------------
__global__ void k_down(const float* __restrict__ agg,
                       const float* __restrict__ z_std, const float* __restrict__ land,
                       const float* __restrict__ Wrel, const float* __restrict__ brel,
                       const float* __restrict__ Wroot,
                       float* __restrict__ x0, float* __restrict__ stats) {
  __shared__ float sstat[2 * cD];
  __shared__ float sWrel[cD * cENC], sWroot[cD * cHIGH_IN], sbrel[cD];
  int tid = threadIdx.x;
  if (tid < 2 * cD) sstat[tid] = 0.0f;
  for (int i = tid; i < cD * cENC; i += 256) sWrel[i] = Wrel[i];
  if (tid < cD * cHIGH_IN) sWroot[tid] = Wroot[tid];
  if (tid < cD) sbrel[tid] = brel[tid];
  __syncthreads();

  int n = blockIdx.x * 256 + tid;
  bool valid = n < cN_HIGH;
  float a[cENC], zz[cHIGH_IN];
  if (valid) {
    const float* ar = agg + (size_t)n * cENC;
    #pragma unroll
    for (int k = 0; k < cENC; ++k) a[k] = ar[k];
    #pragma unroll
    for (int k = 0; k < 6; ++k) zz[k] = z_std[(size_t)n * 6 + k];
    zz[6] = land[n];
  } else {
    #pragma unroll
    for (int k = 0; k < cENC; ++k) a[k] = 0.0f;
    #pragma unroll
    for (int k = 0; k < cHIGH_IN; ++k) zz[k] = 0.0f;
  }
  int lane = tid & 63;
  #pragma unroll
  for (int d = 0; d < cD; ++d) {
    float acc = sbrel[d];
    #pragma unroll
    for (int k = 0; k < cENC; ++k) acc += a[k] * sWrel[d * cENC + k];
    #pragma unroll
    for (int k = 0; k < cHIGH_IN; ++k) acc += zz[k] * sWroot[d * cHIGH_IN + k];
    if (valid) x0[(size_t)n * cD + d] = acc;
    float v = valid ? acc : 0.0f;
    float s1 = v, s2 = v * v;
    #pragma unroll
    for (int o = 32; o > 0; o >>= 1) { s1 += __shfl_down(s1, o); s2 += __shfl_down(s2, o); }
    if (lane == 0) { atomicAdd(&sstat[d], s1); atomicAdd(&sstat[cD + d], s2); }
  }
  __syncthreads();
  if (tid < 2 * cD) atomicAdd(&stats[tid], sstat[tid]);
}

// ---------------- GAT node transform: BN (+relu) + xl/xr ----------------
__global__ void k_transform(const float* __restrict__ xin, const float* __restrict__ stats,
                            const float* __restrict__ g, const float* __restrict__ b,
                            const float* __restrict__ Wl, const float* __restrict__ bl,
                            const float* __restrict__ Wr, const float* __restrict__ br,
                            int applyRelu,
                            float* __restrict__ xl, float* __restrict__ xr) {
  __shared__ float ssc[cD], ssh[cD], sWl[cD * cD], sWr[cD * cD], sbl[cD], sbr[cD];
  int tid = threadIdx.x;
  if (tid < cD) {
    float m = stats[tid] * INV_NHIGH;
    float v = stats[cD + tid] * INV_NHIGH - m * m;
    float sc = g[tid] * rsqrtf(v + cEPS);
    ssc[tid] = sc;
    ssh[tid] = b[tid] - m * sc;
    sbl[tid] = bl[tid];
    sbr[tid] = br[tid];
  }
  if (tid < cD * cD) { sWl[tid] = Wl[tid]; sWr[tid] = Wr[tid]; }
  __syncthreads();

  int n = blockIdx.x * 256 + tid;
  if (n >= cN_HIGH) return;
  float act[cD];
  const float* xp = xin + (size_t)n * cD;
  #pragma unroll
  for (int d = 0; d < cD; ++d) {
    float v = xp[d] * ssc[d] + ssh[d];
    if (applyRelu) v = fmaxf(v, 0.0f);
    act[d] = v;
  }
  float* xlp = xl + (size_t)n * cD;
  float* xrp = xr + (size_t)n * cD;
  #pragma unroll
  for (int d = 0; d < cD; ++d) {
    float al = sbl[d], ar = sbr[d];
    #pragma unroll
    for (int k = 0; k < cD; ++k) { al += act[k] * sWl[d * cD + k]; ar += act[k] * sWr[d * cD + k]; }
    xlp[d] = al;
    xrp[d] = ar;
  }
}

// ---------------- fused GAT edge pass via CSR ----------------
template<int FINAL>
__global__ void k_edge(const float* __restrict__ xl, const float* __restrict__ xr,
                       const int* __restrict__ rowptr, const int* __restrict__ srcs,
                       const float* __restrict__ att, const float* __restrict__ bias,
                       const float* __restrict__ pW, const float* __restrict__ pb,
                       float* __restrict__ xout, float* __restrict__ stats,
                       float* __restrict__ out) {
  __shared__ float satt[cD], sbias[cD];
  __shared__ float sstat[2 * cD];
  int tid = threadIdx.x;
  if (tid < cD) { satt[tid] = att[tid]; sbias[tid] = bias[tid]; }
  if (!FINAL && tid < 2 * cD) sstat[tid] = 0.0f;
  __syncthreads();

  int d = tid & 15;
  int n = blockIdx.x * 16 + (tid >> 4);
  float a_d = satt[d];
  float xr_d = xr[(size_t)n * cD + d];
  float xl_self = xl[(size_t)n * cD + d];

  float v = xl_self + xr_d;
  v = v > 0.0f ? v : cSLOPE * v;
  float p = v * a_d;
  p += __shfl_xor(p, 1); p += __shfl_xor(p, 2); p += __shfl_xor(p, 4); p += __shfl_xor(p, 8);
  float ex = __expf(p);
  float denom = ex;
  float num = ex * xl_self;

  int lo = rowptr[n], hi = rowptr[n + 1];
  for (int i = lo; i < hi; ++i) {
    int s = srcs[i];
    float xls = xl[(size_t)s * cD + d];
    float w = xls + xr_d;
    w = w > 0.0f ? w : cSLOPE * w;
    float q = w * a_d;
    q += __shfl_xor(q, 1); q += __shfl_xor(q, 2); q += __shfl_xor(q, 4); q += __shfl_xor(q, 8);
    float e2 = __expf(q);
    denom += e2;
    num += e2 * xls;
  }
  float cnt = (float)(hi - lo + 1);
  float res = num / denom / cnt + sbias[d];

  if (FINAL) {
    float t = fmaxf(res, 0.0f) * pW[d];
    t += __shfl_xor(t, 1); t += __shfl_xor(t, 2); t += __shfl_xor(t, 4); t += __shfl_xor(t, 8);
    if (d == 0) out[n] = t + pb[0];
  } else {
    xout[(size_t)n * cD + d] = res;
    float s1 = res, s2 = res * res;
    s1 += __shfl_xor(s1, 16); s2 += __shfl_xor(s2, 16);
    s1 += __shfl_xor(s1, 32); s2 += __shfl_xor(s2, 32);
    if ((tid & 63) < 16) { atomicAdd(&sstat[d], s1); atomicAdd(&sstat[cD + d], s2); }
    __syncthreads();
    if (tid < 2 * cD) atomicAdd(&stats[tid], sstat[tid]);
  }
}

// ---------------- launch ----------------
extern "C" void kernel_launch(void* const* d_in, const int* in_sizes, int n_in,
                              void* d_out, int out_size, void* d_ws, size_t ws_size,
                              hipStream_t stream) {
  const float* x_low    = (const float*)d_in[0];
  const float* z_std    = (const float*)d_in[1];
  const float* land     = (const float*)d_in[2];
  const int*   l2h_src  = (const int*)d_in[3];
  const int*   l2h_dst  = (const int*)d_in[4];
  const int*   hh_src   = (const int*)d_in[5];
  const int*   hh_dst   = (const int*)d_in[6];
  const float* gWih     = (const float*)d_in[7];
  const float* gWhh     = (const float*)d_in[8];
  const float* gbih     = (const float*)d_in[9];
  const float* gbhh     = (const float*)d_in[10];
  const float* dW       = (const float*)d_in[11];
  const float* db       = (const float*)d_in[12];
  const float* bn_enc_g = (const float*)d_in[13];
  const float* bn_enc_b = (const float*)d_in[14];
  const float* Wrel     = (const float*)d_in[15];
  const float* brel     = (const float*)d_in[16];
  const float* Wroot    = (const float*)d_in[17];
  const float* gat_Wl   = (const float*)d_in[18];
  const float* gat_bl   = (const float*)d_in[19];
  const float* gat_Wr   = (const float*)d_in[20];
  const float* gat_br   = (const float*)d_in[21];
  const float* gat_att  = (const float*)d_in[22];
  const float* gat_bias = (const float*)d_in[23];
  const float* bn_g     = (const float*)d_in[24];
  const float* bn_b     = (const float*)d_in[25];
  const float* pred_W   = (const float*)d_in[26];
  const float* pred_b   = (const float*)d_in[27];

  float* ws = (float*)d_ws;
  float* hs   = ws + OFF_HS;
  float* agg  = ws + OFF_AGG;
  float* enc  = ws + OFF_ENC;
  float* xA   = ws + OFF_XA;
  float* xB   = ws + OFF_XB;
  float* xl   = ws + OFF_XL;
  float* xr   = ws + OFF_XR;
  float* statsEnc = ws + OFF_STAT;          // 64
  float* statsX   = ws + OFF_STAT + 64;     // 5 x 32
  int* rp_hh  = (int*)(ws + OFF_RPH);
  int* src_hh = (int*)(ws + OFF_SRH);
  int* rp_l2h = (int*)(ws + OFF_RPL);
  int* src_l2h= (int*)(ws + OFF_SRL);
  int* cursor = (int*)(ws + OFF_CUR);
  int* part   = (int*)(ws + OFF_PART);

  hipMemsetAsync(statsEnc, 0, 256 * sizeof(float), stream);

  // --- CSR build: hh ---
  hipMemsetAsync(cursor, 0, cN_HIGH * sizeof(int), stream);
  k_hist<<<(cE_HH + 255) / 256, 256, 0, stream>>>(hh_dst, cE_HH, cursor);
  k_scan_local<<<SC_NB, 256, 0, stream>>>(cursor, cN_HIGH, rp_hh, part);
  k_scan_top<<<1, 256, 0, stream>>>(part, SC_NB, rp_hh + cN_HIGH);
  k_scan_add<<<SC_NB, 256, 0, stream>>>(rp_hh, part, cN_HIGH, cursor);
  k_scatter<<<(cE_HH + 255) / 256, 256, 0, stream>>>(hh_src, hh_dst, cE_HH, cursor, src_hh);
  // --- CSR build: l2h ---
  hipMemsetAsync(cursor, 0, cN_HIGH * sizeof(int), stream);
  k_hist<<<(cE_L2H + 255) / 256, 256, 0, stream>>>(l2h_dst, cE_L2H, cursor);
  k_scan_local<<<SC_NB, 256, 0, stream>>>(cursor, cN_HIGH, rp_l2h, part);
  k_scan_top<<<1, 256, 0, stream>>>(part, SC_NB, rp_l2h + cN_HIGH);
  k_scan_add<<<SC_NB, 256, 0, stream>>>(rp_l2h, part, cN_HIGH, cursor);
  k_scatter<<<(cE_L2H + 255) / 256, 256, 0, stream>>>(l2h_src, l2h_dst, cE_L2H, cursor, src_l2h);

  // --- encoder ---
  k_gru<<<cN_LOW / GRU_NODES, GRU_BLOCK, 0, stream>>>(x_low, gWih, gWhh, gbih, gbhh, hs);
  k_dense<<<cN_LOW / 8, 256, 0, stream>>>(hs, dW, db, enc, statsEnc);
  k_gather_csr<<<cN_HIGH / 8, 256, 0, stream>>>(enc, rp_l2h, src_l2h, statsEnc,
                                                bn_enc_g, bn_enc_b, agg);
  const int NODE_GRID = (cN_HIGH + 255) / 256;
  k_down<<<NODE_GRID, 256, 0, stream>>>(agg, z_std, land, Wrel, brel, Wroot, xA, statsX);

  // --- 5 GATv2 layers ---
  for (int i = 0; i < cNL; ++i) {
    float* xin  = (i & 1) ? xB : xA;
    float* xout = (i & 1) ? xA : xB;
    k_transform<<<NODE_GRID, 256, 0, stream>>>(xin, statsX + 32 * i,
                                               bn_g + 16 * i, bn_b + 16 * i,
                                               gat_Wl + 256 * i, gat_bl + 16 * i,
                                               gat_Wr + 256 * i, gat_br + 16 * i,
                                               (i > 0) ? 1 : 0, xl, xr);
    if (i < cNL - 1) {
      k_edge<0><<<cN_HIGH / 16, 256, 0, stream>>>(xl, xr, rp_hh, src_hh,
                                                  gat_att + 16 * i, gat_bias + 16 * i,
                                                  nullptr, nullptr,
                                                  xout, statsX + 32 * (i + 1), nullptr);
    } else {
      k_edge<1><<<cN_HIGH / 16, 256, 0, stream>>>(xl, xr, rp_hh, src_hh,
                                                  gat_att + 16 * i, gat_bias + 16 * i,
                                                  pred_W, pred_b,
                                                  nullptr, nullptr, (float*)d_out);
    }
  }
}

// Round 4
// 1530.016 us; speedup vs baseline: 5.9076x; 1.0078x over previous
//
#include <hip/hip_runtime.h>
#include <hip/hip_bf16.h>
#include <cstddef>

// ---------------- problem constants ----------------
constexpr int cN_LOW  = 20000;
constexpr int cN_HIGH = 150000;
constexpr int cSEQ = 25;
constexpr int cHIN = 25;
constexpr int cHHID = 25;
constexpr int cENC = 32;
constexpr int cHIGH_IN = 7;
constexpr int cD = 16;
constexpr int cNL = 5;
constexpr int cE_L2H = 1350000;
constexpr int cE_HH = 1200000;
constexpr float cEPS = 1e-5f;
constexpr float cSLOPE = 0.2f;
constexpr float INV_NLOW  = 1.0f / (float)cN_LOW;
constexpr float INV_NHIGH = 1.0f / (float)cN_HIGH;

constexpr int cHSP = 628;     // padded hs row stride (2512 B, 16-aligned)

// scan geometry
constexpr int SC_ELEM = 1024;
constexpr int SC_NB   = (cN_HIGH + SC_ELEM - 1) / SC_ELEM;     // 147
static_assert(SC_NB <= 256, "top scan assumes <=256 partials");

// ---------------- workspace layout (4-byte element offsets) ----------------
constexpr size_t OFF_HS   = 0;                                   // [N_LOW*628]
constexpr size_t SZ_HS    = (size_t)cN_LOW * cHSP;
constexpr size_t OFF_AGG  = 0;                                   // alias (hs dead after k_dense)
constexpr size_t OFF_ENC  = OFF_HS + SZ_HS;                      // [N_LOW*32]
constexpr size_t SZ_ENC   = (size_t)cN_LOW * cENC;
constexpr size_t OFF_XA   = OFF_ENC + SZ_ENC;
constexpr size_t OFF_XB   = OFF_XA + (size_t)cN_HIGH * cD;
constexpr size_t OFF_XL   = OFF_XB + (size_t)cN_HIGH * cD;
constexpr size_t OFF_XR   = OFF_XL + (size_t)cN_HIGH * cD;
constexpr size_t OFF_STAT = OFF_XR + (size_t)cN_HIGH * cD;       // [256]
constexpr size_t OFF_RPH  = OFF_STAT + 256;                      // rowptr_hh [N_HIGH+4]
constexpr size_t OFF_SRH  = OFF_RPH + cN_HIGH + 4;               // src_hh [E_HH]
constexpr size_t OFF_RPL  = OFF_SRH + cE_HH;                     // rowptr_l2h [N_HIGH+4]
constexpr size_t OFF_SRL  = OFF_RPL + cN_HIGH + 4;               // src_l2h [E_L2H]
constexpr size_t OFF_CUR  = OFF_SRL + cE_L2H;                    // cursor [N_HIGH]
constexpr size_t OFF_PART = OFF_CUR + cN_HIGH;                   // partials [256]

// ---------------- GRU kernel ----------------
// thread = (node-in-block, hidden j). Weight rows padded to 28 floats so each
// row is 16B-aligned -> float4 LDS reads (42 b128 instead of 150 b32 per t).
constexpr int GRU_NODES = 10;
constexpr int GRU_BLOCK = GRU_NODES * cHHID;   // 250
constexpr int WP = 28;                          // padded weight/state row stride

__global__ void k_gru(const float* __restrict__ x_low,
                      const float* __restrict__ Wih, const float* __restrict__ Whh,
                      const float* __restrict__ bih, const float* __restrict__ bhh,
                      float* __restrict__ hs) {
  __shared__ __align__(16) float sWih[75 * WP];
  __shared__ __align__(16) float sWhh[75 * WP];
  __shared__ float sbih[75], sbhh[75];
  __shared__ __align__(16) float sx[GRU_NODES][WP];
  __shared__ __align__(16) float sh[GRU_NODES][WP];

  int tid = threadIdx.x;
  // zero (covers pads), then fill
  for (int i = tid; i < 75 * WP; i += GRU_BLOCK) { sWih[i] = 0.0f; sWhh[i] = 0.0f; }
  for (int i = tid; i < GRU_NODES * WP; i += GRU_BLOCK) {
    ((float*)sx)[i] = 0.0f; ((float*)sh)[i] = 0.0f;
  }
  __syncthreads();
  for (int i = tid; i < 75 * 25; i += GRU_BLOCK) {
    int r = i / 25, c = i % 25;
    sWih[r * WP + c] = Wih[i];
    sWhh[r * WP + c] = Whh[i];
  }
  for (int i = tid; i < 75; i += GRU_BLOCK) { sbih[i] = bih[i]; sbhh[i] = bhh[i]; }

  int nl = tid / cHHID;
  int j  = tid % cHHID;
  int n  = blockIdx.x * GRU_NODES + nl;
  __syncthreads();

  const float* xrow = x_low + (size_t)n * 625;
  float* hrow = hs + (size_t)n * cHSP;
  if (j < 3) hrow[625 + j] = 0.0f;      // zero hs row pad for dense float4 reads
  float bihr = sbih[j], bihz = sbih[25 + j], bihn = sbih[50 + j];
  float bhhr = sbhh[j], bhhz = sbhh[25 + j], bhhn = sbhh[50 + j];

  const float4* Wr = (const float4*)(sWih + j * WP);
  const float4* Wz = (const float4*)(sWih + (25 + j) * WP);
  const float4* Wn = (const float4*)(sWih + (50 + j) * WP);
  const float4* Ur = (const float4*)(sWhh + j * WP);
  const float4* Uz = (const float4*)(sWhh + (25 + j) * WP);
  const float4* Un = (const float4*)(sWhh + (50 + j) * WP);
  const float4* X4 = (const float4*)(&sx[nl][0]);
  const float4* H4 = (const float4*)(&sh[nl][0]);

  for (int t = 0; t < cSEQ; ++t) {
    sx[nl][j] = xrow[t * 25 + j];
    __syncthreads();
    float gir = bihr, giz = bihz, gin = bihn;
    float ghr = bhhr, ghz = bhhz, ghn = bhhn;
    #pragma unroll
    for (int c = 0; c < 7; ++c) {
      float4 xv = X4[c], hv = H4[c];
      float4 a = Wr[c], b2 = Wz[c], d2 = Wn[c];
      gir += a.x * xv.x + a.y * xv.y + a.z * xv.z + a.w * xv.w;
      giz += b2.x * xv.x + b2.y * xv.y + b2.z * xv.z + b2.w * xv.w;
      gin += d2.x * xv.x + d2.y * xv.y + d2.z * xv.z + d2.w * xv.w;
      float4 e = Ur[c], f2 = Uz[c], g2 = Un[c];
      ghr += e.x * hv.x + e.y * hv.y + e.z * hv.z + e.w * hv.w;
      ghz += f2.x * hv.x + f2.y * hv.y + f2.z * hv.z + f2.w * hv.w;
      ghn += g2.x * hv.x + g2.y * hv.y + g2.z * hv.z + g2.w * hv.w;
    }
    float r = 1.0f / (1.0f + __expf(-(gir + ghr)));
    float z = 1.0f / (1.0f + __expf(-(giz + ghz)));
    float nn = tanhf(gin + r * ghn);
    float hnew = (1.0f - z) * nn + z * sh[nl][j];
    __syncthreads();
    sh[nl][j] = hnew;
    hrow[t * 25 + j] = hnew;
    __syncthreads();
  }
}

// ---------------- dense 625->32 + relu + BN stats ----------------
// sW padded to stride 628 (2512 B, 16-aligned) for float4 LDS reads; h rows
// padded to 628 so float4 global loads are aligned for every n.
__global__ void k_dense(const float* __restrict__ hs, const float* __restrict__ W,
                        const float* __restrict__ b, float* __restrict__ enc,
                        float* __restrict__ statsEnc) {
  __shared__ __align__(16) float sW[cENC * cHSP];    // 80.4 KB
  __shared__ float sstat[2 * cENC];
  int tid = threadIdx.x;
  for (int i = tid; i < cENC * 625; i += 256) {
    int e2 = i / 625, f2 = i % 625;
    sW[e2 * cHSP + f2] = W[i];
  }
  if (tid < cENC * 3) { int e2 = tid / 3; sW[e2 * cHSP + 625 + tid % 3] = 0.0f; }
  if (tid < 2 * cENC) sstat[tid] = 0.0f;
  __syncthreads();

  int e  = tid & 31;
  int nl = tid >> 5;
  int n  = blockIdx.x * 8 + nl;
  const float4* H4 = (const float4*)(hs + (size_t)n * cHSP);
  const float4* W4 = (const float4*)(sW + e * cHSP);
  float acc = b[e];
  #pragma unroll 4
  for (int f = 0; f < cHSP / 4; ++f) {
    float4 h4 = H4[f], w4 = W4[f];
    acc += h4.x * w4.x + h4.y * w4.y + h4.z * w4.z + h4.w * w4.w;
  }
  float v = fmaxf(acc, 0.0f);
  enc[(size_t)n * cENC + e] = v;

  float p = v + __shfl_down(v, 32);
  float q = v * v + __shfl_down(v * v, 32);
  if ((tid & 63) < 32) { atomicAdd(&sstat[e], p); atomicAdd(&sstat[cENC + e], q); }
  __syncthreads();
  if (tid < 2 * cENC) atomicAdd(&statsEnc[tid], sstat[tid]);
}

// ---------------- CSR build ----------------
__global__ void k_hist(const int* __restrict__ dst, int nE, int* __restrict__ cnt) {
  int e = blockIdx.x * 256 + threadIdx.x;
  if (e < nE) atomicAdd(&cnt[dst[e]], 1);
}

__global__ void k_scan_local(const int* __restrict__ deg, int n,
                             int* __restrict__ out, int* __restrict__ partial) {
  int tid = threadIdx.x;
  int base = blockIdx.x * SC_ELEM + tid * 4;
  int4 v = make_int4(0, 0, 0, 0);
  if (base + 3 < n) v = *(const int4*)(deg + base);
  else { int* pv = (int*)&v; for (int k = 0; k < 4; ++k) if (base + k < n) pv[k] = deg[base + k]; }
  int tsum = v.x + v.y + v.z + v.w;
  int lane = tid & 63;
  int inc = tsum;
  #pragma unroll
  for (int o = 1; o < 64; o <<= 1) { int t = __shfl_up(inc, o); if (lane >= o) inc += t; }
  __shared__ int wtot[4];
  if (lane == 63) wtot[tid >> 6] = inc;
  __syncthreads();
  int w = tid >> 6, wbase = 0;
  #pragma unroll
  for (int k = 0; k < 3; ++k) if (k < w) wbase += wtot[k];
  int ebase = wbase + inc - tsum;
  int4 o4;
  o4.x = ebase; o4.y = ebase + v.x; o4.z = o4.y + v.y; o4.w = o4.z + v.z;
  if (base + 3 < n) *(int4*)(out + base) = o4;
  else { int* po = (int*)&o4; for (int k = 0; k < 4; ++k) if (base + k < n) out[base + k] = po[k]; }
  if (tid == 255) partial[blockIdx.x] = wbase + inc;
}

__global__ void k_scan_top(int* __restrict__ partial, int nb, int* __restrict__ total_out) {
  __shared__ int sd[256];
  int tid = threadIdx.x;
  int v = (tid < nb) ? partial[tid] : 0;
  sd[tid] = v;
  __syncthreads();
  for (int off = 1; off < 256; off <<= 1) {
    int t = (tid >= off) ? sd[tid - off] : 0;
    __syncthreads();
    sd[tid] += t;
    __syncthreads();
  }
  if (tid < nb) partial[tid] = sd[tid] - v;
  if (tid == 255) *total_out = sd[255];
}

__global__ void k_scan_add(int* __restrict__ rowptr, const int* __restrict__ partial,
                           int n, int* __restrict__ cursor) {
  int base = blockIdx.x * SC_ELEM + threadIdx.x * 4;
  int add = partial[blockIdx.x];
  if (base + 3 < n) {
    int4 v = *(int4*)(rowptr + base);
    v.x += add; v.y += add; v.z += add; v.w += add;
    *(int4*)(rowptr + base) = v;
    *(int4*)(cursor + base) = v;
  } else {
    for (int k = 0; k < 4; ++k)
      if (base + k < n) { int t = rowptr[base + k] + add; rowptr[base + k] = t; cursor[base + k] = t; }
  }
}

__global__ void k_scatter(const int* __restrict__ src, const int* __restrict__ dst, int nE,
                          int* __restrict__ cursor, int* __restrict__ out) {
  int e = blockIdx.x * 256 + threadIdx.x;
  if (e < nE) {
    int pos = atomicAdd(&cursor[dst[e]], 1);
    out[pos] = src[e];
  }
}

// ---------------- l2h gather via CSR ----------------
__global__ void k_gather_csr(const float* __restrict__ enc, const int* __restrict__ rowptr,
                             const int* __restrict__ srcs, const float* __restrict__ statsEnc,
                             const float* __restrict__ g, const float* __restrict__ bb,
                             float* __restrict__ agg) {
  __shared__ float ssc[cENC], ssh[cENC];
  int tid = threadIdx.x;
  if (tid < cENC) {
    float m = statsEnc[tid] * INV_NLOW;
    float var = statsEnc[cENC + tid] * INV_NLOW - m * m;
    float sc = g[tid] * rsqrtf(var + cEPS);
    ssc[tid] = sc;
    ssh[tid] = bb[tid] - m * sc;
  }
  __syncthreads();
  int c = tid & 31;
  int n = blockIdx.x * 8 + (tid >> 5);
  int lo = rowptr[n], hi = rowptr[n + 1];
  float sum = 0.0f;
  for (int i = lo; i < hi; ++i) {
    int s = srcs[i];
    sum += enc[(size_t)s * cENC + c];
  }
  float deg = (float)(hi - lo);
  agg[(size_t)n * cENC + c] = (ssc[c] * sum + deg * ssh[c]) / fmaxf(deg, 1.0f);
}

// ---------------- down-projection + BN0 stats ----------------
__global__ void k_down(const float* __restrict__ agg,
                       const float* __restrict__ z_std, const float* __restrict__ land,
                       const float* __restrict__ Wrel, const float* __restrict__ brel,
                       const float* __restrict__ Wroot,
                       float* __restrict__ x0, float* __restrict__ stats) {
  __shared__ float sstat[2 * cD];
  __shared__ float sWrel[cD * cENC], sWroot[cD * cHIGH_IN], sbrel[cD];
  int tid = threadIdx.x;
  if (tid < 2 * cD) sstat[tid] = 0.0f;
  for (int i = tid; i < cD * cENC; i += 256) sWrel[i] = Wrel[i];
  if (tid < cD * cHIGH_IN) sWroot[tid] = Wroot[tid];
  if (tid < cD) sbrel[tid] = brel[tid];
  __syncthreads();

  int n = blockIdx.x * 256 + tid;
  bool valid = n < cN_HIGH;
  float a[cENC], zz[cHIGH_IN];
  if (valid) {
    const float4* ar4 = (const float4*)(agg + (size_t)n * cENC);
    #pragma unroll
    for (int k = 0; k < cENC / 4; ++k) {
      float4 t4 = ar4[k];
      a[4*k] = t4.x; a[4*k+1] = t4.y; a[4*k+2] = t4.z; a[4*k+3] = t4.w;
    }
    #pragma unroll
    for (int k = 0; k < 6; ++k) zz[k] = z_std[(size_t)n * 6 + k];
    zz[6] = land[n];
  } else {
    #pragma unroll
    for (int k = 0; k < cENC; ++k) a[k] = 0.0f;
    #pragma unroll
    for (int k = 0; k < cHIGH_IN; ++k) zz[k] = 0.0f;
  }
  int lane = tid & 63;
  #pragma unroll
  for (int d = 0; d < cD; ++d) {
    float acc = sbrel[d];
    #pragma unroll
    for (int k = 0; k < cENC; ++k) acc += a[k] * sWrel[d * cENC + k];
    #pragma unroll
    for (int k = 0; k < cHIGH_IN; ++k) acc += zz[k] * sWroot[d * cHIGH_IN + k];
    if (valid) x0[(size_t)n * cD + d] = acc;
    float v = valid ? acc : 0.0f;
    float s1 = v, s2 = v * v;
    #pragma unroll
    for (int o = 32; o > 0; o >>= 1) { s1 += __shfl_down(s1, o); s2 += __shfl_down(s2, o); }
    if (lane == 0) { atomicAdd(&sstat[d], s1); atomicAdd(&sstat[cD + d], s2); }
  }
  __syncthreads();
  if (tid < 2 * cD) atomicAdd(&stats[tid], sstat[tid]);
}

// ---------------- GAT node transform ----------------
__global__ void k_transform(const float* __restrict__ xin, const float* __restrict__ stats,
                            const float* __restrict__ g, const float* __restrict__ b,
                            const float* __restrict__ Wl, const float* __restrict__ bl,
                            const float* __restrict__ Wr, const float* __restrict__ br,
                            int applyRelu,
                            float* __restrict__ xl, float* __restrict__ xr) {
  __shared__ float ssc[cD], ssh[cD], sWl[cD * cD], sWr[cD * cD], sbl[cD], sbr[cD];
  int tid = threadIdx.x;
  if (tid < cD) {
    float m = stats[tid] * INV_NHIGH;
    float v = stats[cD + tid] * INV_NHIGH - m * m;
    float sc = g[tid] * rsqrtf(v + cEPS);
    ssc[tid] = sc;
    ssh[tid] = b[tid] - m * sc;
    sbl[tid] = bl[tid];
    sbr[tid] = br[tid];
  }
  if (tid < cD * cD) { sWl[tid] = Wl[tid]; sWr[tid] = Wr[tid]; }
  __syncthreads();

  int n = blockIdx.x * 256 + tid;
  if (n >= cN_HIGH) return;
  float act[cD];
  const float* xp = xin + (size_t)n * cD;
  #pragma unroll
  for (int d = 0; d < cD; ++d) {
    float v = xp[d] * ssc[d] + ssh[d];
    if (applyRelu) v = fmaxf(v, 0.0f);
    act[d] = v;
  }
  float* xlp = xl + (size_t)n * cD;
  float* xrp = xr + (size_t)n * cD;
  #pragma unroll
  for (int d = 0; d < cD; ++d) {
    float al = sbl[d], ar = sbr[d];
    #pragma unroll
    for (int k = 0; k < cD; ++k) { al += act[k] * sWl[d * cD + k]; ar += act[k] * sWr[d * cD + k]; }
    xlp[d] = al;
    xrp[d] = ar;
  }
}

// ---------------- fused GAT edge pass via CSR ----------------
template<int FINAL>
__global__ void k_edge(const float* __restrict__ xl, const float* __restrict__ xr,
                       const int* __restrict__ rowptr, const int* __restrict__ srcs,
                       const float* __restrict__ att, const float* __restrict__ bias,
                       const float* __restrict__ pW, const float* __restrict__ pb,
                       float* __restrict__ xout, float* __restrict__ stats,
                       float* __restrict__ out) {
  __shared__ float satt[cD], sbias[cD];
  __shared__ float sstat[2 * cD];
  int tid = threadIdx.x;
  if (tid < cD) { satt[tid] = att[tid]; sbias[tid] = bias[tid]; }
  if (!FINAL && tid < 2 * cD) sstat[tid] = 0.0f;
  __syncthreads();

  int d = tid & 15;
  int n = blockIdx.x * 16 + (tid >> 4);
  float a_d = satt[d];
  float xr_d = xr[(size_t)n * cD + d];
  float xl_self = xl[(size_t)n * cD + d];

  float v = xl_self + xr_d;
  v = v > 0.0f ? v : cSLOPE * v;
  float p = v * a_d;
  p += __shfl_xor(p, 1); p += __shfl_xor(p, 2); p += __shfl_xor(p, 4); p += __shfl_xor(p, 8);
  float ex = __expf(p);
  float denom = ex;
  float num = ex * xl_self;

  int lo = rowptr[n], hi = rowptr[n + 1];
  for (int i = lo; i < hi; ++i) {
    int s = srcs[i];
    float xls = xl[(size_t)s * cD + d];
    float w = xls + xr_d;
    w = w > 0.0f ? w : cSLOPE * w;
    float q = w * a_d;
    q += __shfl_xor(q, 1); q += __shfl_xor(q, 2); q += __shfl_xor(q, 4); q += __shfl_xor(q, 8);
    float e2 = __expf(q);
    denom += e2;
    num += e2 * xls;
  }
  float cnt = (float)(hi - lo + 1);
  float res = num / denom / cnt + sbias[d];

  if (FINAL) {
    float t = fmaxf(res, 0.0f) * pW[d];
    t += __shfl_xor(t, 1); t += __shfl_xor(t, 2); t += __shfl_xor(t, 4); t += __shfl_xor(t, 8);
    if (d == 0) out[n] = t + pb[0];
  } else {
    xout[(size_t)n * cD + d] = res;
    float s1 = res, s2 = res * res;
    s1 += __shfl_xor(s1, 16); s2 += __shfl_xor(s2, 16);
    s1 += __shfl_xor(s1, 32); s2 += __shfl_xor(s2, 32);
    if ((tid & 63) < 16) { atomicAdd(&sstat[d], s1); atomicAdd(&sstat[cD + d], s2); }
    __syncthreads();
    if (tid < 2 * cD) atomicAdd(&stats[tid], sstat[tid]);
  }
}

// ---------------- launch ----------------
extern "C" void kernel_launch(void* const* d_in, const int* in_sizes, int n_in,
                              void* d_out, int out_size, void* d_ws, size_t ws_size,
                              hipStream_t stream) {
  const float* x_low    = (const float*)d_in[0];
  const float* z_std    = (const float*)d_in[1];
  const float* land     = (const float*)d_in[2];
  const int*   l2h_src  = (const int*)d_in[3];
  const int*   l2h_dst  = (const int*)d_in[4];
  const int*   hh_src   = (const int*)d_in[5];
  const int*   hh_dst   = (const int*)d_in[6];
  const float* gWih     = (const float*)d_in[7];
  const float* gWhh     = (const float*)d_in[8];
  const float* gbih     = (const float*)d_in[9];
  const float* gbhh     = (const float*)d_in[10];
  const float* dW       = (const float*)d_in[11];
  const float* db       = (const float*)d_in[12];
  const float* bn_enc_g = (const float*)d_in[13];
  const float* bn_enc_b = (const float*)d_in[14];
  const float* Wrel     = (const float*)d_in[15];
  const float* brel     = (const float*)d_in[16];
  const float* Wroot    = (const float*)d_in[17];
  const float* gat_Wl   = (const float*)d_in[18];
  const float* gat_bl   = (const float*)d_in[19];
  const float* gat_Wr   = (const float*)d_in[20];
  const float* gat_br   = (const float*)d_in[21];
  const float* gat_att  = (const float*)d_in[22];
  const float* gat_bias = (const float*)d_in[23];
  const float* bn_g     = (const float*)d_in[24];
  const float* bn_b     = (const float*)d_in[25];
  const float* pred_W   = (const float*)d_in[26];
  const float* pred_b   = (const float*)d_in[27];

  float* ws = (float*)d_ws;
  float* hs   = ws + OFF_HS;
  float* agg  = ws + OFF_AGG;
  float* enc  = ws + OFF_ENC;
  float* xA   = ws + OFF_XA;
  float* xB   = ws + OFF_XB;
  float* xl   = ws + OFF_XL;
  float* xr   = ws + OFF_XR;
  float* statsEnc = ws + OFF_STAT;
  float* statsX   = ws + OFF_STAT + 64;
  int* rp_hh  = (int*)(ws + OFF_RPH);
  int* src_hh = (int*)(ws + OFF_SRH);
  int* rp_l2h = (int*)(ws + OFF_RPL);
  int* src_l2h= (int*)(ws + OFF_SRL);
  int* cursor = (int*)(ws + OFF_CUR);
  int* part   = (int*)(ws + OFF_PART);

  hipMemsetAsync(statsEnc, 0, 256 * sizeof(float), stream);

  // --- CSR build: hh ---
  hipMemsetAsync(cursor, 0, cN_HIGH * sizeof(int), stream);
  k_hist<<<(cE_HH + 255) / 256, 256, 0, stream>>>(hh_dst, cE_HH, cursor);
  k_scan_local<<<SC_NB, 256, 0, stream>>>(cursor, cN_HIGH, rp_hh, part);
  k_scan_top<<<1, 256, 0, stream>>>(part, SC_NB, rp_hh + cN_HIGH);
  k_scan_add<<<SC_NB, 256, 0, stream>>>(rp_hh, part, cN_HIGH, cursor);
  k_scatter<<<(cE_HH + 255) / 256, 256, 0, stream>>>(hh_src, hh_dst, cE_HH, cursor, src_hh);
  // --- CSR build: l2h ---
  hipMemsetAsync(cursor, 0, cN_HIGH * sizeof(int), stream);
  k_hist<<<(cE_L2H + 255) / 256, 256, 0, stream>>>(l2h_dst, cE_L2H, cursor);
  k_scan_local<<<SC_NB, 256, 0, stream>>>(cursor, cN_HIGH, rp_l2h, part);
  k_scan_top<<<1, 256, 0, stream>>>(part, SC_NB, rp_l2h + cN_HIGH);
  k_scan_add<<<SC_NB, 256, 0, stream>>>(rp_l2h, part, cN_HIGH, cursor);
  k_scatter<<<(cE_L2H + 255) / 256, 256, 0, stream>>>(l2h_src, l2h_dst, cE_L2H, cursor, src_l2h);

  // --- encoder ---
  k_gru<<<cN_LOW / GRU_NODES, GRU_BLOCK, 0, stream>>>(x_low, gWih, gWhh, gbih, gbhh, hs);
  k_dense<<<cN_LOW / 8, 256, 0, stream>>>(hs, dW, db, enc, statsEnc);
  k_gather_csr<<<cN_HIGH / 8, 256, 0, stream>>>(enc, rp_l2h, src_l2h, statsEnc,
                                                bn_enc_g, bn_enc_b, agg);
  const int NODE_GRID = (cN_HIGH + 255) / 256;
  k_down<<<NODE_GRID, 256, 0, stream>>>(agg, z_std, land, Wrel, brel, Wroot, xA, statsX);

  // --- 5 GATv2 layers ---
  for (int i = 0; i < cNL; ++i) {
    float* xin  = (i & 1) ? xB : xA;
    float* xout = (i & 1) ? xA : xB;
    k_transform<<<NODE_GRID, 256, 0, stream>>>(xin, statsX + 32 * i,
                                               bn_g + 16 * i, bn_b + 16 * i,
                                               gat_Wl + 256 * i, gat_bl + 16 * i,
                                               gat_Wr + 256 * i, gat_br + 16 * i,
                                               (i > 0) ? 1 : 0, xl, xr);
    if (i < cNL - 1) {
      k_edge<0><<<cN_HIGH / 16, 256, 0, stream>>>(xl, xr, rp_hh, src_hh,
                                                  gat_att + 16 * i, gat_bias + 16 * i,
                                                  nullptr, nullptr,
                                                  xout, statsX + 32 * (i + 1), nullptr);
    } else {
      k_edge<1><<<cN_HIGH / 16, 256, 0, stream>>>(xl, xr, rp_hh, src_hh,
                                                  gat_att + 16 * i, gat_bias + 16 * i,
                                                  pred_W, pred_b,
                                                  nullptr, nullptr, (float*)d_out);
    }
  }
}

// Round 5
// 1513.458 us; speedup vs baseline: 5.9723x; 1.0109x over previous
//
#include <hip/hip_runtime.h>
#include <hip/hip_bf16.h>
#include <cstddef>

// ---------------- problem constants ----------------
constexpr int cN_LOW  = 20000;
constexpr int cN_HIGH = 150000;
constexpr int cSEQ = 25;
constexpr int cHIN = 25;
constexpr int cHHID = 25;
constexpr int cENC = 32;
constexpr int cHIGH_IN = 7;
constexpr int cD = 16;
constexpr int cNL = 5;
constexpr int cE_L2H = 1350000;
constexpr int cE_HH = 1200000;
constexpr float cEPS = 1e-5f;
constexpr float cSLOPE = 0.2f;
constexpr float INV_NLOW  = 1.0f / (float)cN_LOW;
constexpr float INV_NHIGH = 1.0f / (float)cN_HIGH;

constexpr int cHSP = 628;     // padded hs row stride (16B-aligned rows)

// scan geometry
constexpr int SC_ELEM = 1024;
constexpr int SC_NB   = (cN_HIGH + SC_ELEM - 1) / SC_ELEM;     // 147
static_assert(SC_NB <= 256, "top scan assumes <=256 partials");

// ---------------- workspace layout (4-byte element offsets) ----------------
constexpr size_t OFF_HS   = 0;                                   // [N_LOW*628]
constexpr size_t SZ_HS    = (size_t)cN_LOW * cHSP;
constexpr size_t OFF_AGG  = 0;                                   // alias (hs dead after k_dense)
constexpr size_t OFF_ENC  = OFF_HS + SZ_HS;                      // [N_LOW*32]
constexpr size_t SZ_ENC   = (size_t)cN_LOW * cENC;
constexpr size_t OFF_XA   = OFF_ENC + SZ_ENC;
constexpr size_t OFF_XB   = OFF_XA + (size_t)cN_HIGH * cD;
constexpr size_t OFF_XL   = OFF_XB + (size_t)cN_HIGH * cD;
constexpr size_t OFF_XR   = OFF_XL + (size_t)cN_HIGH * cD;
constexpr size_t OFF_STAT = OFF_XR + (size_t)cN_HIGH * cD;       // [256]
constexpr size_t OFF_RPH  = OFF_STAT + 256;                      // rowptr_hh [N_HIGH+4]
constexpr size_t OFF_SRH  = OFF_RPH + cN_HIGH + 4;               // src_hh [E_HH]
constexpr size_t OFF_RPL  = OFF_SRH + cE_HH;                     // rowptr_l2h [N_HIGH+4]
constexpr size_t OFF_SRL  = OFF_RPL + cN_HIGH + 4;               // src_l2h [E_L2H]
constexpr size_t OFF_CUR  = OFF_SRL + cE_L2H;                    // cursor [N_HIGH]
constexpr size_t OFF_PART = OFF_CUR + cN_HIGH;                   // partials [256]

__device__ __forceinline__ float fast_sigmoid(float a) {
  return __builtin_amdgcn_rcpf(1.0f + __expf(-a));
}
__device__ __forceinline__ float fast_tanh(float a) {
  float t = __expf(-2.0f * a);
  return (1.0f - t) * __builtin_amdgcn_rcpf(1.0f + t);
}

// ---------------- GRU kernel ----------------
// Weight rows padded to 26 floats (8B-aligned, odd*2) -> float2 LDS reads with
// at most 2-way bank aliasing (free per m136). b128 is structurally conflicted
// at these shapes (stride%4==0 => j vs j+8 alias) -- measured r4 regression.
constexpr int GRU_NODES = 10;
constexpr int GRU_BLOCK = GRU_NODES * cHHID;   // 250
constexpr int WP = 26;                          // padded weight/state row stride

__global__ void k_gru(const float* __restrict__ x_low,
                      const float* __restrict__ Wih, const float* __restrict__ Whh,
                      const float* __restrict__ bih, const float* __restrict__ bhh,
                      float* __restrict__ hs) {
  __shared__ __align__(8) float sWih[75 * WP];
  __shared__ __align__(8) float sWhh[75 * WP];
  __shared__ float sbih[75], sbhh[75];
  __shared__ __align__(8) float sx[GRU_NODES][WP];
  __shared__ __align__(8) float sh[GRU_NODES][WP];

  int tid = threadIdx.x;
  for (int i = tid; i < 75 * WP; i += GRU_BLOCK) { sWih[i] = 0.0f; sWhh[i] = 0.0f; }
  for (int i = tid; i < GRU_NODES * WP; i += GRU_BLOCK) {
    ((float*)sx)[i] = 0.0f; ((float*)sh)[i] = 0.0f;
  }
  __syncthreads();
  for (int i = tid; i < 75 * 25; i += GRU_BLOCK) {
    int r = i / 25, c = i % 25;
    sWih[r * WP + c] = Wih[i];
    sWhh[r * WP + c] = Whh[i];
  }
  for (int i = tid; i < 75; i += GRU_BLOCK) { sbih[i] = bih[i]; sbhh[i] = bhh[i]; }

  int nl = tid / cHHID;
  int j  = tid % cHHID;
  int n  = blockIdx.x * GRU_NODES + nl;
  __syncthreads();

  const float* xrow = x_low + (size_t)n * 625;
  float* hrow = hs + (size_t)n * cHSP;
  if (j < 3) hrow[625 + j] = 0.0f;      // zero hs row pad for dense float4 reads
  float bihr = sbih[j], bihz = sbih[25 + j], bihn = sbih[50 + j];
  float bhhr = sbhh[j], bhhz = sbhh[25 + j], bhhn = sbhh[50 + j];

  const float2* Wr = (const float2*)(sWih + j * WP);
  const float2* Wz = (const float2*)(sWih + (25 + j) * WP);
  const float2* Wn = (const float2*)(sWih + (50 + j) * WP);
  const float2* Ur = (const float2*)(sWhh + j * WP);
  const float2* Uz = (const float2*)(sWhh + (25 + j) * WP);
  const float2* Un = (const float2*)(sWhh + (50 + j) * WP);
  const float2* X2 = (const float2*)(&sx[nl][0]);
  const float2* H2 = (const float2*)(&sh[nl][0]);

  for (int t = 0; t < cSEQ; ++t) {
    sx[nl][j] = xrow[t * 25 + j];
    __syncthreads();
    float gir = bihr, giz = bihz, gin = bihn;
    float ghr = bhhr, ghz = bhhz, ghn = bhhn;
    #pragma unroll
    for (int c = 0; c < 13; ++c) {
      float2 xv = X2[c], hv = H2[c];
      float2 a = Wr[c], b2 = Wz[c], d2 = Wn[c];
      gir += a.x * xv.x + a.y * xv.y;
      giz += b2.x * xv.x + b2.y * xv.y;
      gin += d2.x * xv.x + d2.y * xv.y;
      float2 e = Ur[c], f2 = Uz[c], g2 = Un[c];
      ghr += e.x * hv.x + e.y * hv.y;
      ghz += f2.x * hv.x + f2.y * hv.y;
      ghn += g2.x * hv.x + g2.y * hv.y;
    }
    float r = fast_sigmoid(gir + ghr);
    float z = fast_sigmoid(giz + ghz);
    float nn = fast_tanh(gin + r * ghn);
    float hnew = (1.0f - z) * nn + z * sh[nl][j];
    __syncthreads();
    sh[nl][j] = hnew;
    hrow[t * 25 + j] = hnew;
    __syncthreads();
  }
}

// ---------------- dense 625->32 + relu + BN stats ----------------
__global__ void k_dense(const float* __restrict__ hs, const float* __restrict__ W,
                        const float* __restrict__ b, float* __restrict__ enc,
                        float* __restrict__ statsEnc) {
  __shared__ __align__(16) float sW[cENC * cHSP];    // 80.4 KB
  __shared__ float sstat[2 * cENC];
  int tid = threadIdx.x;
  for (int i = tid; i < cENC * 625; i += 256) {
    int e2 = i / 625, f2 = i % 625;
    sW[e2 * cHSP + f2] = W[i];
  }
  if (tid < cENC * 3) { int e2 = tid / 3; sW[e2 * cHSP + 625 + tid % 3] = 0.0f; }
  if (tid < 2 * cENC) sstat[tid] = 0.0f;
  __syncthreads();

  int e  = tid & 31;
  int nl = tid >> 5;
  int n  = blockIdx.x * 8 + nl;
  const float4* H4 = (const float4*)(hs + (size_t)n * cHSP);
  const float4* W4 = (const float4*)(sW + e * cHSP);
  float acc = b[e];
  #pragma unroll 4
  for (int f = 0; f < cHSP / 4; ++f) {
    float4 h4 = H4[f], w4 = W4[f];
    acc += h4.x * w4.x + h4.y * w4.y + h4.z * w4.z + h4.w * w4.w;
  }
  float v = fmaxf(acc, 0.0f);
  enc[(size_t)n * cENC + e] = v;

  float p = v + __shfl_down(v, 32);
  float q = v * v + __shfl_down(v * v, 32);
  if ((tid & 63) < 32) { atomicAdd(&sstat[e], p); atomicAdd(&sstat[cENC + e], q); }
  __syncthreads();
  if (tid < 2 * cENC) atomicAdd(&statsEnc[tid], sstat[tid]);
}

// ---------------- CSR build ----------------
__global__ void k_hist(const int* __restrict__ dst, int nE, int* __restrict__ cnt) {
  int e = blockIdx.x * 256 + threadIdx.x;
  if (e < nE) atomicAdd(&cnt[dst[e]], 1);
}

__global__ void k_scan_local(const int* __restrict__ deg, int n,
                             int* __restrict__ out, int* __restrict__ partial) {
  int tid = threadIdx.x;
  int base = blockIdx.x * SC_ELEM + tid * 4;
  int4 v = make_int4(0, 0, 0, 0);
  if (base + 3 < n) v = *(const int4*)(deg + base);
  else { int* pv = (int*)&v; for (int k = 0; k < 4; ++k) if (base + k < n) pv[k] = deg[base + k]; }
  int tsum = v.x + v.y + v.z + v.w;
  int lane = tid & 63;
  int inc = tsum;
  #pragma unroll
  for (int o = 1; o < 64; o <<= 1) { int t = __shfl_up(inc, o); if (lane >= o) inc += t; }
  __shared__ int wtot[4];
  if (lane == 63) wtot[tid >> 6] = inc;
  __syncthreads();
  int w = tid >> 6, wbase = 0;
  #pragma unroll
  for (int k = 0; k < 3; ++k) if (k < w) wbase += wtot[k];
  int ebase = wbase + inc - tsum;
  int4 o4;
  o4.x = ebase; o4.y = ebase + v.x; o4.z = o4.y + v.y; o4.w = o4.z + v.z;
  if (base + 3 < n) *(int4*)(out + base) = o4;
  else { int* po = (int*)&o4; for (int k = 0; k < 4; ++k) if (base + k < n) out[base + k] = po[k]; }
  if (tid == 255) partial[blockIdx.x] = wbase + inc;
}

__global__ void k_scan_top(int* __restrict__ partial, int nb, int* __restrict__ total_out) {
  __shared__ int sd[256];
  int tid = threadIdx.x;
  int v = (tid < nb) ? partial[tid] : 0;
  sd[tid] = v;
  __syncthreads();
  for (int off = 1; off < 256; off <<= 1) {
    int t = (tid >= off) ? sd[tid - off] : 0;
    __syncthreads();
    sd[tid] += t;
    __syncthreads();
  }
  if (tid < nb) partial[tid] = sd[tid] - v;
  if (tid == 255) *total_out = sd[255];
}

__global__ void k_scan_add(int* __restrict__ rowptr, const int* __restrict__ partial,
                           int n, int* __restrict__ cursor) {
  int base = blockIdx.x * SC_ELEM + threadIdx.x * 4;
  int add = partial[blockIdx.x];
  if (base + 3 < n) {
    int4 v = *(int4*)(rowptr + base);
    v.x += add; v.y += add; v.z += add; v.w += add;
    *(int4*)(rowptr + base) = v;
    *(int4*)(cursor + base) = v;
  } else {
    for (int k = 0; k < 4; ++k)
      if (base + k < n) { int t = rowptr[base + k] + add; rowptr[base + k] = t; cursor[base + k] = t; }
  }
}

__global__ void k_scatter(const int* __restrict__ src, const int* __restrict__ dst, int nE,
                          int* __restrict__ cursor, int* __restrict__ out) {
  int e = blockIdx.x * 256 + threadIdx.x;
  if (e < nE) {
    int pos = atomicAdd(&cursor[dst[e]], 1);
    out[pos] = src[e];
  }
}

// ---------------- l2h gather via CSR ----------------
__global__ void k_gather_csr(const float* __restrict__ enc, const int* __restrict__ rowptr,
                             const int* __restrict__ srcs, const float* __restrict__ statsEnc,
                             const float* __restrict__ g, const float* __restrict__ bb,
                             float* __restrict__ agg) {
  __shared__ float ssc[cENC], ssh[cENC];
  int tid = threadIdx.x;
  if (tid < cENC) {
    float m = statsEnc[tid] * INV_NLOW;
    float var = statsEnc[cENC + tid] * INV_NLOW - m * m;
    float sc = g[tid] * rsqrtf(var + cEPS);
    ssc[tid] = sc;
    ssh[tid] = bb[tid] - m * sc;
  }
  __syncthreads();
  int c = tid & 31;
  int n = blockIdx.x * 8 + (tid >> 5);
  int lo = rowptr[n], hi = rowptr[n + 1];
  float sum = 0.0f;
  for (int i = lo; i < hi; ++i) {
    int s = srcs[i];
    sum += enc[(size_t)s * cENC + c];
  }
  float deg = (float)(hi - lo);
  agg[(size_t)n * cENC + c] = (ssc[c] * sum + deg * ssh[c]) / fmaxf(deg, 1.0f);
}

// ---------------- down-projection + BN0 stats ----------------
__global__ void k_down(const float* __restrict__ agg,
                       const float* __restrict__ z_std, const float* __restrict__ land,
                       const float* __restrict__ Wrel, const float* __restrict__ brel,
                       const float* __restrict__ Wroot,
                       float* __restrict__ x0, float* __restrict__ stats) {
  __shared__ float sstat[2 * cD];
  __shared__ float sWrel[cD * cENC], sWroot[cD * cHIGH_IN], sbrel[cD];
  int tid = threadIdx.x;
  if (tid < 2 * cD) sstat[tid] = 0.0f;
  for (int i = tid; i < cD * cENC; i += 256) sWrel[i] = Wrel[i];
  if (tid < cD * cHIGH_IN) sWroot[tid] = Wroot[tid];
  if (tid < cD) sbrel[tid] = brel[tid];
  __syncthreads();

  int n = blockIdx.x * 256 + tid;
  bool valid = n < cN_HIGH;
  float a[cENC], zz[cHIGH_IN];
  if (valid) {
    const float4* ar4 = (const float4*)(agg + (size_t)n * cENC);
    #pragma unroll
    for (int k = 0; k < cENC / 4; ++k) {
      float4 t4 = ar4[k];
      a[4*k] = t4.x; a[4*k+1] = t4.y; a[4*k+2] = t4.z; a[4*k+3] = t4.w;
    }
    #pragma unroll
    for (int k = 0; k < 6; ++k) zz[k] = z_std[(size_t)n * 6 + k];
    zz[6] = land[n];
  } else {
    #pragma unroll
    for (int k = 0; k < cENC; ++k) a[k] = 0.0f;
    #pragma unroll
    for (int k = 0; k < cHIGH_IN; ++k) zz[k] = 0.0f;
  }
  int lane = tid & 63;
  #pragma unroll
  for (int d = 0; d < cD; ++d) {
    float acc = sbrel[d];
    #pragma unroll
    for (int k = 0; k < cENC; ++k) acc += a[k] * sWrel[d * cENC + k];
    #pragma unroll
    for (int k = 0; k < cHIGH_IN; ++k) acc += zz[k] * sWroot[d * cHIGH_IN + k];
    if (valid) x0[(size_t)n * cD + d] = acc;
    float v = valid ? acc : 0.0f;
    float s1 = v, s2 = v * v;
    #pragma unroll
    for (int o = 32; o > 0; o >>= 1) { s1 += __shfl_down(s1, o); s2 += __shfl_down(s2, o); }
    if (lane == 0) { atomicAdd(&sstat[d], s1); atomicAdd(&sstat[cD + d], s2); }
  }
  __syncthreads();
  if (tid < 2 * cD) atomicAdd(&stats[tid], sstat[tid]);
}

// ---------------- GAT node transform ----------------
__global__ void k_transform(const float* __restrict__ xin, const float* __restrict__ stats,
                            const float* __restrict__ g, const float* __restrict__ b,
                            const float* __restrict__ Wl, const float* __restrict__ bl,
                            const float* __restrict__ Wr, const float* __restrict__ br,
                            int applyRelu,
                            float* __restrict__ xl, float* __restrict__ xr) {
  __shared__ float ssc[cD], ssh[cD], sWl[cD * cD], sWr[cD * cD], sbl[cD], sbr[cD];
  int tid = threadIdx.x;
  if (tid < cD) {
    float m = stats[tid] * INV_NHIGH;
    float v = stats[cD + tid] * INV_NHIGH - m * m;
    float sc = g[tid] * rsqrtf(v + cEPS);
    ssc[tid] = sc;
    ssh[tid] = b[tid] - m * sc;
    sbl[tid] = bl[tid];
    sbr[tid] = br[tid];
  }
  if (tid < cD * cD) { sWl[tid] = Wl[tid]; sWr[tid] = Wr[tid]; }
  __syncthreads();

  int n = blockIdx.x * 256 + tid;
  if (n >= cN_HIGH) return;
  float act[cD];
  const float* xp = xin + (size_t)n * cD;
  #pragma unroll
  for (int d = 0; d < cD; ++d) {
    float v = xp[d] * ssc[d] + ssh[d];
    if (applyRelu) v = fmaxf(v, 0.0f);
    act[d] = v;
  }
  float* xlp = xl + (size_t)n * cD;
  float* xrp = xr + (size_t)n * cD;
  #pragma unroll
  for (int d = 0; d < cD; ++d) {
    float al = sbl[d], ar = sbr[d];
    #pragma unroll
    for (int k = 0; k < cD; ++k) { al += act[k] * sWl[d * cD + k]; ar += act[k] * sWr[d * cD + k]; }
    xlp[d] = al;
    xrp[d] = ar;
  }
}

// ---------------- fused GAT edge pass via CSR (2-way unrolled) ----------------
template<int FINAL>
__global__ void k_edge(const float* __restrict__ xl, const float* __restrict__ xr,
                       const int* __restrict__ rowptr, const int* __restrict__ srcs,
                       const float* __restrict__ att, const float* __restrict__ bias,
                       const float* __restrict__ pW, const float* __restrict__ pb,
                       float* __restrict__ xout, float* __restrict__ stats,
                       float* __restrict__ out) {
  __shared__ float satt[cD], sbias[cD];
  __shared__ float sstat[2 * cD];
  int tid = threadIdx.x;
  if (tid < cD) { satt[tid] = att[tid]; sbias[tid] = bias[tid]; }
  if (!FINAL && tid < 2 * cD) sstat[tid] = 0.0f;
  __syncthreads();

  int d = tid & 15;
  int n = blockIdx.x * 16 + (tid >> 4);
  float a_d = satt[d];
  float xr_d = xr[(size_t)n * cD + d];
  float xl_self = xl[(size_t)n * cD + d];

  float v = xl_self + xr_d;
  v = v > 0.0f ? v : cSLOPE * v;
  float p = v * a_d;
  p += __shfl_xor(p, 1); p += __shfl_xor(p, 2); p += __shfl_xor(p, 4); p += __shfl_xor(p, 8);
  float ex = __expf(p);
  float denom = ex;
  float num = ex * xl_self;

  int lo = rowptr[n], hi = rowptr[n + 1];
  int i = lo;
  for (; i + 1 < hi; i += 2) {
    int s0 = srcs[i], s1 = srcs[i + 1];
    float x0 = xl[(size_t)s0 * cD + d];
    float x1 = xl[(size_t)s1 * cD + d];
    float w0 = x0 + xr_d; w0 = w0 > 0.0f ? w0 : cSLOPE * w0;
    float w1 = x1 + xr_d; w1 = w1 > 0.0f ? w1 : cSLOPE * w1;
    float q0 = w0 * a_d, q1 = w1 * a_d;
    q0 += __shfl_xor(q0, 1); q1 += __shfl_xor(q1, 1);
    q0 += __shfl_xor(q0, 2); q1 += __shfl_xor(q1, 2);
    q0 += __shfl_xor(q0, 4); q1 += __shfl_xor(q1, 4);
    q0 += __shfl_xor(q0, 8); q1 += __shfl_xor(q1, 8);
    float e0 = __expf(q0), e1 = __expf(q1);
    denom += e0 + e1;
    num += e0 * x0 + e1 * x1;
  }
  if (i < hi) {
    int s = srcs[i];
    float xls = xl[(size_t)s * cD + d];
    float w = xls + xr_d;
    w = w > 0.0f ? w : cSLOPE * w;
    float q = w * a_d;
    q += __shfl_xor(q, 1); q += __shfl_xor(q, 2); q += __shfl_xor(q, 4); q += __shfl_xor(q, 8);
    float e2 = __expf(q);
    denom += e2;
    num += e2 * xls;
  }
  float cnt = (float)(hi - lo + 1);
  float res = num / denom / cnt + sbias[d];

  if (FINAL) {
    float t = fmaxf(res, 0.0f) * pW[d];
    t += __shfl_xor(t, 1); t += __shfl_xor(t, 2); t += __shfl_xor(t, 4); t += __shfl_xor(t, 8);
    if (d == 0) out[n] = t + pb[0];
  } else {
    xout[(size_t)n * cD + d] = res;
    float s1 = res, s2 = res * res;
    s1 += __shfl_xor(s1, 16); s2 += __shfl_xor(s2, 16);
    s1 += __shfl_xor(s1, 32); s2 += __shfl_xor(s2, 32);
    if ((tid & 63) < 16) { atomicAdd(&sstat[d], s1); atomicAdd(&sstat[cD + d], s2); }
    __syncthreads();
    if (tid < 2 * cD) atomicAdd(&stats[tid], sstat[tid]);
  }
}

// ---------------- launch ----------------
extern "C" void kernel_launch(void* const* d_in, const int* in_sizes, int n_in,
                              void* d_out, int out_size, void* d_ws, size_t ws_size,
                              hipStream_t stream) {
  const float* x_low    = (const float*)d_in[0];
  const float* z_std    = (const float*)d_in[1];
  const float* land     = (const float*)d_in[2];
  const int*   l2h_src  = (const int*)d_in[3];
  const int*   l2h_dst  = (const int*)d_in[4];
  const int*   hh_src   = (const int*)d_in[5];
  const int*   hh_dst   = (const int*)d_in[6];
  const float* gWih     = (const float*)d_in[7];
  const float* gWhh     = (const float*)d_in[8];
  const float* gbih     = (const float*)d_in[9];
  const float* gbhh     = (const float*)d_in[10];
  const float* dW       = (const float*)d_in[11];
  const float* db       = (const float*)d_in[12];
  const float* bn_enc_g = (const float*)d_in[13];
  const float* bn_enc_b = (const float*)d_in[14];
  const float* Wrel     = (const float*)d_in[15];
  const float* brel     = (const float*)d_in[16];
  const float* Wroot    = (const float*)d_in[17];
  const float* gat_Wl   = (const float*)d_in[18];
  const float* gat_bl   = (const float*)d_in[19];
  const float* gat_Wr   = (const float*)d_in[20];
  const float* gat_br   = (const float*)d_in[21];
  const float* gat_att  = (const float*)d_in[22];
  const float* gat_bias = (const float*)d_in[23];
  const float* bn_g     = (const float*)d_in[24];
  const float* bn_b     = (const float*)d_in[25];
  const float* pred_W   = (const float*)d_in[26];
  const float* pred_b   = (const float*)d_in[27];

  float* ws = (float*)d_ws;
  float* hs   = ws + OFF_HS;
  float* agg  = ws + OFF_AGG;
  float* enc  = ws + OFF_ENC;
  float* xA   = ws + OFF_XA;
  float* xB   = ws + OFF_XB;
  float* xl   = ws + OFF_XL;
  float* xr   = ws + OFF_XR;
  float* statsEnc = ws + OFF_STAT;
  float* statsX   = ws + OFF_STAT + 64;
  int* rp_hh  = (int*)(ws + OFF_RPH);
  int* src_hh = (int*)(ws + OFF_SRH);
  int* rp_l2h = (int*)(ws + OFF_RPL);
  int* src_l2h= (int*)(ws + OFF_SRL);
  int* cursor = (int*)(ws + OFF_CUR);
  int* part   = (int*)(ws + OFF_PART);

  hipMemsetAsync(statsEnc, 0, 256 * sizeof(float), stream);

  // --- CSR build: hh ---
  hipMemsetAsync(cursor, 0, cN_HIGH * sizeof(int), stream);
  k_hist<<<(cE_HH + 255) / 256, 256, 0, stream>>>(hh_dst, cE_HH, cursor);
  k_scan_local<<<SC_NB, 256, 0, stream>>>(cursor, cN_HIGH, rp_hh, part);
  k_scan_top<<<1, 256, 0, stream>>>(part, SC_NB, rp_hh + cN_HIGH);
  k_scan_add<<<SC_NB, 256, 0, stream>>>(rp_hh, part, cN_HIGH, cursor);
  k_scatter<<<(cE_HH + 255) / 256, 256, 0, stream>>>(hh_src, hh_dst, cE_HH, cursor, src_hh);
  // --- CSR build: l2h ---
  hipMemsetAsync(cursor, 0, cN_HIGH * sizeof(int), stream);
  k_hist<<<(cE_L2H + 255) / 256, 256, 0, stream>>>(l2h_dst, cE_L2H, cursor);
  k_scan_local<<<SC_NB, 256, 0, stream>>>(cursor, cN_HIGH, rp_l2h, part);
  k_scan_top<<<1, 256, 0, stream>>>(part, SC_NB, rp_l2h + cN_HIGH);
  k_scan_add<<<SC_NB, 256, 0, stream>>>(rp_l2h, part, cN_HIGH, cursor);
  k_scatter<<<(cE_L2H + 255) / 256, 256, 0, stream>>>(l2h_src, l2h_dst, cE_L2H, cursor, src_l2h);

  // --- encoder ---
  k_gru<<<cN_LOW / GRU_NODES, GRU_BLOCK, 0, stream>>>(x_low, gWih, gWhh, gbih, gbhh, hs);
  k_dense<<<cN_LOW / 8, 256, 0, stream>>>(hs, dW, db, enc, statsEnc);
  k_gather_csr<<<cN_HIGH / 8, 256, 0, stream>>>(enc, rp_l2h, src_l2h, statsEnc,
                                                bn_enc_g, bn_enc_b, agg);
  const int NODE_GRID = (cN_HIGH + 255) / 256;
  k_down<<<NODE_GRID, 256, 0, stream>>>(agg, z_std, land, Wrel, brel, Wroot, xA, statsX);

  // --- 5 GATv2 layers ---
  for (int i = 0; i < cNL; ++i) {
    float* xin  = (i & 1) ? xB : xA;
    float* xout = (i & 1) ? xA : xB;
    k_transform<<<NODE_GRID, 256, 0, stream>>>(xin, statsX + 32 * i,
                                               bn_g + 16 * i, bn_b + 16 * i,
                                               gat_Wl + 256 * i, gat_bl + 16 * i,
                                               gat_Wr + 256 * i, gat_br + 16 * i,
                                               (i > 0) ? 1 : 0, xl, xr);
    if (i < cNL - 1) {
      k_edge<0><<<cN_HIGH / 16, 256, 0, stream>>>(xl, xr, rp_hh, src_hh,
                                                  gat_att + 16 * i, gat_bias + 16 * i,
                                                  nullptr, nullptr,
                                                  xout, statsX + 32 * (i + 1), nullptr);
    } else {
      k_edge<1><<<cN_HIGH / 16, 256, 0, stream>>>(xl, xr, rp_hh, src_hh,
                                                  gat_att + 16 * i, gat_bias + 16 * i,
                                                  pred_W, pred_b,
                                                  nullptr, nullptr, (float*)d_out);
    }
  }
}

// Round 6
// 1421.182 us; speedup vs baseline: 6.3600x; 1.0649x over previous
//
#include <hip/hip_runtime.h>
#include <hip/hip_bf16.h>
#include <cstddef>

// ---------------- problem constants ----------------
constexpr int cN_LOW  = 20000;
constexpr int cN_HIGH = 150000;
constexpr int cSEQ = 25;
constexpr int cHIN = 25;
constexpr int cHHID = 25;
constexpr int cENC = 32;
constexpr int cHIGH_IN = 7;
constexpr int cD = 16;
constexpr int cNL = 5;
constexpr int cE_L2H = 1350000;
constexpr int cE_HH = 1200000;
constexpr float cEPS = 1e-5f;
constexpr float cSLOPE = 0.2f;
constexpr float INV_NLOW  = 1.0f / (float)cN_LOW;
constexpr float INV_NHIGH = 1.0f / (float)cN_HIGH;

constexpr int cHSP = 628;     // padded hs row stride (16B-aligned rows)

// scan geometry
constexpr int SC_ELEM = 1024;
constexpr int SC_NB   = (cN_HIGH + SC_ELEM - 1) / SC_ELEM;     // 147
static_assert(SC_NB <= 256, "top scan assumes <=256 partials");

// ---------------- workspace layout (4-byte element offsets) ----------------
constexpr size_t OFF_HS   = 0;                                   // [N_LOW*628]
constexpr size_t SZ_HS    = (size_t)cN_LOW * cHSP;
constexpr size_t OFF_AGG  = 0;                                   // alias (hs dead after k_dense)
constexpr size_t OFF_ENC  = OFF_HS + SZ_HS;                      // [N_LOW*32]
constexpr size_t SZ_ENC   = (size_t)cN_LOW * cENC;
constexpr size_t OFF_XA   = OFF_ENC + SZ_ENC;
constexpr size_t OFF_XB   = OFF_XA + (size_t)cN_HIGH * cD;
constexpr size_t OFF_XL   = OFF_XB + (size_t)cN_HIGH * cD;
constexpr size_t OFF_XR   = OFF_XL + (size_t)cN_HIGH * cD;
constexpr size_t OFF_STAT = OFF_XR + (size_t)cN_HIGH * cD;       // [256]
constexpr size_t OFF_RPH  = OFF_STAT + 256;                      // rowptr_hh [N_HIGH+4]
constexpr size_t OFF_SRH  = OFF_RPH + cN_HIGH + 4;               // src_hh [E_HH]
constexpr size_t OFF_RPL  = OFF_SRH + cE_HH;                     // rowptr_l2h [N_HIGH+4]
constexpr size_t OFF_SRL  = OFF_RPL + cN_HIGH + 4;               // src_l2h [E_L2H]
constexpr size_t OFF_CUR  = OFF_SRL + cE_L2H;                    // cursor [N_HIGH]
constexpr size_t OFF_PART = OFF_CUR + cN_HIGH;                   // partials [256]

__device__ __forceinline__ float fast_sigmoid(float a) {
  return __builtin_amdgcn_rcpf(1.0f + __expf(-a));
}
__device__ __forceinline__ float fast_tanh(float a) {
  float t = __expf(-2.0f * a);
  return (1.0f - t) * __builtin_amdgcn_rcpf(1.0f + t);
}

// ---------------- GRU kernel ----------------
// Weights live in VGPRs (150/thread: the 6 fixed rows for this thread's j).
// Only x/h go through LDS, both double-buffered -> 1 barrier per timestep.
// r3/r4/r5 showed the kernel is weight-operand-read bound, not FLOP bound:
// LDS-vectorization attempts regressed (b64/b128 bank aliasing at stride
// 26/28); register-holding removes the 150 LDS reads/t entirely.
constexpr int GRU_NODES = 10;
constexpr int GRU_BLOCK = GRU_NODES * cHHID;   // 250

__global__ __launch_bounds__(256, 2)
void k_gru(const float* __restrict__ x_low,
           const float* __restrict__ Wih, const float* __restrict__ Whh,
           const float* __restrict__ bih, const float* __restrict__ bhh,
           float* __restrict__ hs) {
  __shared__ float sx[2][GRU_NODES][cHIN];
  __shared__ float sh[2][GRU_NODES][cHHID];

  int tid = threadIdx.x;
  int nl = tid / cHHID;           // 0..9
  int j  = tid % cHHID;           // 0..24
  int n  = blockIdx.x * GRU_NODES + nl;

  // register-resident weights
  float wr[25], wz[25], wn[25], ur[25], uz[25], un[25];
  #pragma unroll
  for (int i = 0; i < 25; ++i) {
    wr[i] = Wih[j * 25 + i];
    wz[i] = Wih[(25 + j) * 25 + i];
    wn[i] = Wih[(50 + j) * 25 + i];
    ur[i] = Whh[j * 25 + i];
    uz[i] = Whh[(25 + j) * 25 + i];
    un[i] = Whh[(50 + j) * 25 + i];
  }
  float br = bih[j], bz = bih[25 + j], bn2 = bih[50 + j];
  float cr = bhh[j], cz = bhh[25 + j], cn = bhh[50 + j];

  const float* xrow = x_low + (size_t)n * 625;
  float* hrow = hs + (size_t)n * cHSP;
  if (j < 3) hrow[625 + j] = 0.0f;       // zero hs row pad for dense float4 reads

  sh[0][nl][j] = 0.0f;
  sx[0][nl][j] = xrow[j];                // x for t=0
  __syncthreads();

  int p = 0;   // current h buffer
  int q = 0;   // current x buffer
  for (int t = 0; t < cSEQ; ++t) {
    if (t + 1 < cSEQ) sx[q ^ 1][nl][j] = xrow[(t + 1) * 25 + j];   // prefetch next x
    float gr = br + cr, gz = bz + cz, gni = bn2, gnh = cn;
    #pragma unroll
    for (int i = 0; i < 25; ++i) {
      float xv = sx[q][nl][i];
      float hv = sh[p][nl][i];
      gr  += wr[i] * xv + ur[i] * hv;
      gz  += wz[i] * xv + uz[i] * hv;
      gni += wn[i] * xv;
      gnh += un[i] * hv;
    }
    float r = fast_sigmoid(gr);
    float z = fast_sigmoid(gz);
    float nn = fast_tanh(gni + r * gnh);
    float hnew = (1.0f - z) * nn + z * sh[p][nl][j];
    sh[p ^ 1][nl][j] = hnew;
    hrow[t * 25 + j] = hnew;
    p ^= 1;
    q ^= 1;
    __syncthreads();
  }
}

// ---------------- dense 625->32 + relu + BN stats ----------------
__global__ void k_dense(const float* __restrict__ hs, const float* __restrict__ W,
                        const float* __restrict__ b, float* __restrict__ enc,
                        float* __restrict__ statsEnc) {
  __shared__ __align__(16) float sW[cENC * cHSP];    // 80.4 KB
  __shared__ float sstat[2 * cENC];
  int tid = threadIdx.x;
  for (int i = tid; i < cENC * 625; i += 256) {
    int e2 = i / 625, f2 = i % 625;
    sW[e2 * cHSP + f2] = W[i];
  }
  if (tid < cENC * 3) { int e2 = tid / 3; sW[e2 * cHSP + 625 + tid % 3] = 0.0f; }
  if (tid < 2 * cENC) sstat[tid] = 0.0f;
  __syncthreads();

  int e  = tid & 31;
  int nl = tid >> 5;
  int n  = blockIdx.x * 8 + nl;
  const float4* H4 = (const float4*)(hs + (size_t)n * cHSP);
  const float4* W4 = (const float4*)(sW + e * cHSP);
  float acc = b[e];
  #pragma unroll 4
  for (int f = 0; f < cHSP / 4; ++f) {
    float4 h4 = H4[f], w4 = W4[f];
    acc += h4.x * w4.x + h4.y * w4.y + h4.z * w4.z + h4.w * w4.w;
  }
  float v = fmaxf(acc, 0.0f);
  enc[(size_t)n * cENC + e] = v;

  float p = v + __shfl_down(v, 32);
  float q = v * v + __shfl_down(v * v, 32);
  if ((tid & 63) < 32) { atomicAdd(&sstat[e], p); atomicAdd(&sstat[cENC + e], q); }
  __syncthreads();
  if (tid < 2 * cENC) atomicAdd(&statsEnc[tid], sstat[tid]);
}

// ---------------- CSR build ----------------
__global__ void k_hist(const int* __restrict__ dst, int nE, int* __restrict__ cnt) {
  int e = blockIdx.x * 256 + threadIdx.x;
  if (e < nE) atomicAdd(&cnt[dst[e]], 1);
}

__global__ void k_scan_local(const int* __restrict__ deg, int n,
                             int* __restrict__ out, int* __restrict__ partial) {
  int tid = threadIdx.x;
  int base = blockIdx.x * SC_ELEM + tid * 4;
  int4 v = make_int4(0, 0, 0, 0);
  if (base + 3 < n) v = *(const int4*)(deg + base);
  else { int* pv = (int*)&v; for (int k = 0; k < 4; ++k) if (base + k < n) pv[k] = deg[base + k]; }
  int tsum = v.x + v.y + v.z + v.w;
  int lane = tid & 63;
  int inc = tsum;
  #pragma unroll
  for (int o = 1; o < 64; o <<= 1) { int t = __shfl_up(inc, o); if (lane >= o) inc += t; }
  __shared__ int wtot[4];
  if (lane == 63) wtot[tid >> 6] = inc;
  __syncthreads();
  int w = tid >> 6, wbase = 0;
  #pragma unroll
  for (int k = 0; k < 3; ++k) if (k < w) wbase += wtot[k];
  int ebase = wbase + inc - tsum;
  int4 o4;
  o4.x = ebase; o4.y = ebase + v.x; o4.z = o4.y + v.y; o4.w = o4.z + v.z;
  if (base + 3 < n) *(int4*)(out + base) = o4;
  else { int* po = (int*)&o4; for (int k = 0; k < 4; ++k) if (base + k < n) out[base + k] = po[k]; }
  if (tid == 255) partial[blockIdx.x] = wbase + inc;
}

__global__ void k_scan_top(int* __restrict__ partial, int nb, int* __restrict__ total_out) {
  __shared__ int sd[256];
  int tid = threadIdx.x;
  int v = (tid < nb) ? partial[tid] : 0;
  sd[tid] = v;
  __syncthreads();
  for (int off = 1; off < 256; off <<= 1) {
    int t = (tid >= off) ? sd[tid - off] : 0;
    __syncthreads();
    sd[tid] += t;
    __syncthreads();
  }
  if (tid < nb) partial[tid] = sd[tid] - v;
  if (tid == 255) *total_out = sd[255];
}

__global__ void k_scan_add(int* __restrict__ rowptr, const int* __restrict__ partial,
                           int n, int* __restrict__ cursor) {
  int base = blockIdx.x * SC_ELEM + threadIdx.x * 4;
  int add = partial[blockIdx.x];
  if (base + 3 < n) {
    int4 v = *(int4*)(rowptr + base);
    v.x += add; v.y += add; v.z += add; v.w += add;
    *(int4*)(rowptr + base) = v;
    *(int4*)(cursor + base) = v;
  } else {
    for (int k = 0; k < 4; ++k)
      if (base + k < n) { int t = rowptr[base + k] + add; rowptr[base + k] = t; cursor[base + k] = t; }
  }
}

__global__ void k_scatter(const int* __restrict__ src, const int* __restrict__ dst, int nE,
                          int* __restrict__ cursor, int* __restrict__ out) {
  int e = blockIdx.x * 256 + threadIdx.x;
  if (e < nE) {
    int pos = atomicAdd(&cursor[dst[e]], 1);
    out[pos] = src[e];
  }
}

// ---------------- l2h gather via CSR ----------------
__global__ void k_gather_csr(const float* __restrict__ enc, const int* __restrict__ rowptr,
                             const int* __restrict__ srcs, const float* __restrict__ statsEnc,
                             const float* __restrict__ g, const float* __restrict__ bb,
                             float* __restrict__ agg) {
  __shared__ float ssc[cENC], ssh[cENC];
  int tid = threadIdx.x;
  if (tid < cENC) {
    float m = statsEnc[tid] * INV_NLOW;
    float var = statsEnc[cENC + tid] * INV_NLOW - m * m;
    float sc = g[tid] * rsqrtf(var + cEPS);
    ssc[tid] = sc;
    ssh[tid] = bb[tid] - m * sc;
  }
  __syncthreads();
  int c = tid & 31;
  int n = blockIdx.x * 8 + (tid >> 5);
  int lo = rowptr[n], hi = rowptr[n + 1];
  float sum = 0.0f;
  for (int i = lo; i < hi; ++i) {
    int s = srcs[i];
    sum += enc[(size_t)s * cENC + c];
  }
  float deg = (float)(hi - lo);
  agg[(size_t)n * cENC + c] = (ssc[c] * sum + deg * ssh[c]) / fmaxf(deg, 1.0f);
}

// ---------------- down-projection + BN0 stats ----------------
__global__ void k_down(const float* __restrict__ agg,
                       const float* __restrict__ z_std, const float* __restrict__ land,
                       const float* __restrict__ Wrel, const float* __restrict__ brel,
                       const float* __restrict__ Wroot,
                       float* __restrict__ x0, float* __restrict__ stats) {
  __shared__ float sstat[2 * cD];
  __shared__ float sWrel[cD * cENC], sWroot[cD * cHIGH_IN], sbrel[cD];
  int tid = threadIdx.x;
  if (tid < 2 * cD) sstat[tid] = 0.0f;
  for (int i = tid; i < cD * cENC; i += 256) sWrel[i] = Wrel[i];
  if (tid < cD * cHIGH_IN) sWroot[tid] = Wroot[tid];
  if (tid < cD) sbrel[tid] = brel[tid];
  __syncthreads();

  int n = blockIdx.x * 256 + tid;
  bool valid = n < cN_HIGH;
  float a[cENC], zz[cHIGH_IN];
  if (valid) {
    const float4* ar4 = (const float4*)(agg + (size_t)n * cENC);
    #pragma unroll
    for (int k = 0; k < cENC / 4; ++k) {
      float4 t4 = ar4[k];
      a[4*k] = t4.x; a[4*k+1] = t4.y; a[4*k+2] = t4.z; a[4*k+3] = t4.w;
    }
    #pragma unroll
    for (int k = 0; k < 6; ++k) zz[k] = z_std[(size_t)n * 6 + k];
    zz[6] = land[n];
  } else {
    #pragma unroll
    for (int k = 0; k < cENC; ++k) a[k] = 0.0f;
    #pragma unroll
    for (int k = 0; k < cHIGH_IN; ++k) zz[k] = 0.0f;
  }
  int lane = tid & 63;
  #pragma unroll
  for (int d = 0; d < cD; ++d) {
    float acc = sbrel[d];
    #pragma unroll
    for (int k = 0; k < cENC; ++k) acc += a[k] * sWrel[d * cENC + k];
    #pragma unroll
    for (int k = 0; k < cHIGH_IN; ++k) acc += zz[k] * sWroot[d * cHIGH_IN + k];
    if (valid) x0[(size_t)n * cD + d] = acc;
    float v = valid ? acc : 0.0f;
    float s1 = v, s2 = v * v;
    #pragma unroll
    for (int o = 32; o > 0; o >>= 1) { s1 += __shfl_down(s1, o); s2 += __shfl_down(s2, o); }
    if (lane == 0) { atomicAdd(&sstat[d], s1); atomicAdd(&sstat[cD + d], s2); }
  }
  __syncthreads();
  if (tid < 2 * cD) atomicAdd(&stats[tid], sstat[tid]);
}

// ---------------- GAT node transform ----------------
__global__ void k_transform(const float* __restrict__ xin, const float* __restrict__ stats,
                            const float* __restrict__ g, const float* __restrict__ b,
                            const float* __restrict__ Wl, const float* __restrict__ bl,
                            const float* __restrict__ Wr, const float* __restrict__ br,
                            int applyRelu,
                            float* __restrict__ xl, float* __restrict__ xr) {
  __shared__ float ssc[cD], ssh[cD], sWl[cD * cD], sWr[cD * cD], sbl[cD], sbr[cD];
  int tid = threadIdx.x;
  if (tid < cD) {
    float m = stats[tid] * INV_NHIGH;
    float v = stats[cD + tid] * INV_NHIGH - m * m;
    float sc = g[tid] * rsqrtf(v + cEPS);
    ssc[tid] = sc;
    ssh[tid] = b[tid] - m * sc;
    sbl[tid] = bl[tid];
    sbr[tid] = br[tid];
  }
  if (tid < cD * cD) { sWl[tid] = Wl[tid]; sWr[tid] = Wr[tid]; }
  __syncthreads();

  int n = blockIdx.x * 256 + tid;
  if (n >= cN_HIGH) return;
  float act[cD];
  const float* xp = xin + (size_t)n * cD;
  #pragma unroll
  for (int d = 0; d < cD; ++d) {
    float v = xp[d] * ssc[d] + ssh[d];
    if (applyRelu) v = fmaxf(v, 0.0f);
    act[d] = v;
  }
  float* xlp = xl + (size_t)n * cD;
  float* xrp = xr + (size_t)n * cD;
  #pragma unroll
  for (int d = 0; d < cD; ++d) {
    float al = sbl[d], ar = sbr[d];
    #pragma unroll
    for (int k = 0; k < cD; ++k) { al += act[k] * sWl[d * cD + k]; ar += act[k] * sWr[d * cD + k]; }
    xlp[d] = al;
    xrp[d] = ar;
  }
}

// ---------------- fused GAT edge pass via CSR (4-way unrolled) ----------------
template<int FINAL>
__global__ void k_edge(const float* __restrict__ xl, const float* __restrict__ xr,
                       const int* __restrict__ rowptr, const int* __restrict__ srcs,
                       const float* __restrict__ att, const float* __restrict__ bias,
                       const float* __restrict__ pW, const float* __restrict__ pb,
                       float* __restrict__ xout, float* __restrict__ stats,
                       float* __restrict__ out) {
  __shared__ float satt[cD], sbias[cD];
  __shared__ float sstat[2 * cD];
  int tid = threadIdx.x;
  if (tid < cD) { satt[tid] = att[tid]; sbias[tid] = bias[tid]; }
  if (!FINAL && tid < 2 * cD) sstat[tid] = 0.0f;
  __syncthreads();

  int d = tid & 15;
  int n = blockIdx.x * 16 + (tid >> 4);
  float a_d = satt[d];
  float xr_d = xr[(size_t)n * cD + d];
  float xl_self = xl[(size_t)n * cD + d];

  float v = xl_self + xr_d;
  v = v > 0.0f ? v : cSLOPE * v;
  float p = v * a_d;
  p += __shfl_xor(p, 1); p += __shfl_xor(p, 2); p += __shfl_xor(p, 4); p += __shfl_xor(p, 8);
  float ex = __expf(p);
  float denom = ex;
  float num = ex * xl_self;

  int lo = rowptr[n], hi = rowptr[n + 1];
  int i = lo;
  for (; i + 3 < hi; i += 4) {
    int s0 = srcs[i], s1 = srcs[i + 1], s2 = srcs[i + 2], s3 = srcs[i + 3];
    float x0 = xl[(size_t)s0 * cD + d];
    float x1 = xl[(size_t)s1 * cD + d];
    float x2 = xl[(size_t)s2 * cD + d];
    float x3 = xl[(size_t)s3 * cD + d];
    float w0 = x0 + xr_d; w0 = w0 > 0.0f ? w0 : cSLOPE * w0;
    float w1 = x1 + xr_d; w1 = w1 > 0.0f ? w1 : cSLOPE * w1;
    float w2 = x2 + xr_d; w2 = w2 > 0.0f ? w2 : cSLOPE * w2;
    float w3 = x3 + xr_d; w3 = w3 > 0.0f ? w3 : cSLOPE * w3;
    float q0 = w0 * a_d, q1 = w1 * a_d, q2 = w2 * a_d, q3 = w3 * a_d;
    q0 += __shfl_xor(q0, 1); q1 += __shfl_xor(q1, 1); q2 += __shfl_xor(q2, 1); q3 += __shfl_xor(q3, 1);
    q0 += __shfl_xor(q0, 2); q1 += __shfl_xor(q1, 2); q2 += __shfl_xor(q2, 2); q3 += __shfl_xor(q3, 2);
    q0 += __shfl_xor(q0, 4); q1 += __shfl_xor(q1, 4); q2 += __shfl_xor(q2, 4); q3 += __shfl_xor(q3, 4);
    q0 += __shfl_xor(q0, 8); q1 += __shfl_xor(q1, 8); q2 += __shfl_xor(q2, 8); q3 += __shfl_xor(q3, 8);
    float e0 = __expf(q0), e1 = __expf(q1), e2c = __expf(q2), e3 = __expf(q3);
    denom += (e0 + e1) + (e2c + e3);
    num += e0 * x0 + e1 * x1 + e2c * x2 + e3 * x3;
  }
  for (; i < hi; ++i) {
    int s = srcs[i];
    float xls = xl[(size_t)s * cD + d];
    float w = xls + xr_d;
    w = w > 0.0f ? w : cSLOPE * w;
    float q = w * a_d;
    q += __shfl_xor(q, 1); q += __shfl_xor(q, 2); q += __shfl_xor(q, 4); q += __shfl_xor(q, 8);
    float e2 = __expf(q);
    denom += e2;
    num += e2 * xls;
  }
  float cnt = (float)(hi - lo + 1);
  float res = num / denom / cnt + sbias[d];

  if (FINAL) {
    float t = fmaxf(res, 0.0f) * pW[d];
    t += __shfl_xor(t, 1); t += __shfl_xor(t, 2); t += __shfl_xor(t, 4); t += __shfl_xor(t, 8);
    if (d == 0) out[n] = t + pb[0];
  } else {
    xout[(size_t)n * cD + d] = res;
    float s1 = res, s2 = res * res;
    s1 += __shfl_xor(s1, 16); s2 += __shfl_xor(s2, 16);
    s1 += __shfl_xor(s1, 32); s2 += __shfl_xor(s2, 32);
    if ((tid & 63) < 16) { atomicAdd(&sstat[d], s1); atomicAdd(&sstat[cD + d], s2); }
    __syncthreads();
    if (tid < 2 * cD) atomicAdd(&stats[tid], sstat[tid]);
  }
}

// ---------------- launch ----------------
extern "C" void kernel_launch(void* const* d_in, const int* in_sizes, int n_in,
                              void* d_out, int out_size, void* d_ws, size_t ws_size,
                              hipStream_t stream) {
  const float* x_low    = (const float*)d_in[0];
  const float* z_std    = (const float*)d_in[1];
  const float* land     = (const float*)d_in[2];
  const int*   l2h_src  = (const int*)d_in[3];
  const int*   l2h_dst  = (const int*)d_in[4];
  const int*   hh_src   = (const int*)d_in[5];
  const int*   hh_dst   = (const int*)d_in[6];
  const float* gWih     = (const float*)d_in[7];
  const float* gWhh     = (const float*)d_in[8];
  const float* gbih     = (const float*)d_in[9];
  const float* gbhh     = (const float*)d_in[10];
  const float* dW       = (const float*)d_in[11];
  const float* db       = (const float*)d_in[12];
  const float* bn_enc_g = (const float*)d_in[13];
  const float* bn_enc_b = (const float*)d_in[14];
  const float* Wrel     = (const float*)d_in[15];
  const float* brel     = (const float*)d_in[16];
  const float* Wroot    = (const float*)d_in[17];
  const float* gat_Wl   = (const float*)d_in[18];
  const float* gat_bl   = (const float*)d_in[19];
  const float* gat_Wr   = (const float*)d_in[20];
  const float* gat_br   = (const float*)d_in[21];
  const float* gat_att  = (const float*)d_in[22];
  const float* gat_bias = (const float*)d_in[23];
  const float* bn_g     = (const float*)d_in[24];
  const float* bn_b     = (const float*)d_in[25];
  const float* pred_W   = (const float*)d_in[26];
  const float* pred_b   = (const float*)d_in[27];

  float* ws = (float*)d_ws;
  float* hs   = ws + OFF_HS;
  float* agg  = ws + OFF_AGG;
  float* enc  = ws + OFF_ENC;
  float* xA   = ws + OFF_XA;
  float* xB   = ws + OFF_XB;
  float* xl   = ws + OFF_XL;
  float* xr   = ws + OFF_XR;
  float* statsEnc = ws + OFF_STAT;
  float* statsX   = ws + OFF_STAT + 64;
  int* rp_hh  = (int*)(ws + OFF_RPH);
  int* src_hh = (int*)(ws + OFF_SRH);
  int* rp_l2h = (int*)(ws + OFF_RPL);
  int* src_l2h= (int*)(ws + OFF_SRL);
  int* cursor = (int*)(ws + OFF_CUR);
  int* part   = (int*)(ws + OFF_PART);

  hipMemsetAsync(statsEnc, 0, 256 * sizeof(float), stream);

  // --- CSR build: hh ---
  hipMemsetAsync(cursor, 0, cN_HIGH * sizeof(int), stream);
  k_hist<<<(cE_HH + 255) / 256, 256, 0, stream>>>(hh_dst, cE_HH, cursor);
  k_scan_local<<<SC_NB, 256, 0, stream>>>(cursor, cN_HIGH, rp_hh, part);
  k_scan_top<<<1, 256, 0, stream>>>(part, SC_NB, rp_hh + cN_HIGH);
  k_scan_add<<<SC_NB, 256, 0, stream>>>(rp_hh, part, cN_HIGH, cursor);
  k_scatter<<<(cE_HH + 255) / 256, 256, 0, stream>>>(hh_src, hh_dst, cE_HH, cursor, src_hh);
  // --- CSR build: l2h ---
  hipMemsetAsync(cursor, 0, cN_HIGH * sizeof(int), stream);
  k_hist<<<(cE_L2H + 255) / 256, 256, 0, stream>>>(l2h_dst, cE_L2H, cursor);
  k_scan_local<<<SC_NB, 256, 0, stream>>>(cursor, cN_HIGH, rp_l2h, part);
  k_scan_top<<<1, 256, 0, stream>>>(part, SC_NB, rp_l2h + cN_HIGH);
  k_scan_add<<<SC_NB, 256, 0, stream>>>(rp_l2h, part, cN_HIGH, cursor);
  k_scatter<<<(cE_L2H + 255) / 256, 256, 0, stream>>>(l2h_src, l2h_dst, cE_L2H, cursor, src_l2h);

  // --- encoder ---
  k_gru<<<cN_LOW / GRU_NODES, GRU_BLOCK, 0, stream>>>(x_low, gWih, gWhh, gbih, gbhh, hs);
  k_dense<<<cN_LOW / 8, 256, 0, stream>>>(hs, dW, db, enc, statsEnc);
  k_gather_csr<<<cN_HIGH / 8, 256, 0, stream>>>(enc, rp_l2h, src_l2h, statsEnc,
                                                bn_enc_g, bn_enc_b, agg);
  const int NODE_GRID = (cN_HIGH + 255) / 256;
  k_down<<<NODE_GRID, 256, 0, stream>>>(agg, z_std, land, Wrel, brel, Wroot, xA, statsX);

  // --- 5 GATv2 layers ---
  for (int i = 0; i < cNL; ++i) {
    float* xin  = (i & 1) ? xB : xA;
    float* xout = (i & 1) ? xA : xB;
    k_transform<<<NODE_GRID, 256, 0, stream>>>(xin, statsX + 32 * i,
                                               bn_g + 16 * i, bn_b + 16 * i,
                                               gat_Wl + 256 * i, gat_bl + 16 * i,
                                               gat_Wr + 256 * i, gat_br + 16 * i,
                                               (i > 0) ? 1 : 0, xl, xr);
    if (i < cNL - 1) {
      k_edge<0><<<cN_HIGH / 16, 256, 0, stream>>>(xl, xr, rp_hh, src_hh,
                                                  gat_att + 16 * i, gat_bias + 16 * i,
                                                  nullptr, nullptr,
                                                  xout, statsX + 32 * (i + 1), nullptr);
    } else {
      k_edge<1><<<cN_HIGH / 16, 256, 0, stream>>>(xl, xr, rp_hh, src_hh,
                                                  gat_att + 16 * i, gat_bias + 16 * i,
                                                  pred_W, pred_b,
                                                  nullptr, nullptr, (float*)d_out);
    }
  }
}

// Round 7
// 1394.535 us; speedup vs baseline: 6.4816x; 1.0191x over previous
//
#include <hip/hip_runtime.h>
#include <hip/hip_bf16.h>
#include <cstddef>

// ---------------- problem constants ----------------
constexpr int cN_LOW  = 20000;
constexpr int cN_HIGH = 150000;
constexpr int cSEQ = 25;
constexpr int cHIN = 25;
constexpr int cHHID = 25;
constexpr int cENC = 32;
constexpr int cHIGH_IN = 7;
constexpr int cD = 16;
constexpr int cNL = 5;
constexpr int cE_L2H = 1350000;
constexpr int cE_HH = 1200000;
constexpr float cEPS = 1e-5f;
constexpr float cSLOPE = 0.2f;
constexpr float INV_NLOW  = 1.0f / (float)cN_LOW;
constexpr float INV_NHIGH = 1.0f / (float)cN_HIGH;

constexpr int cHSP = 628;     // padded hs row stride (16B-aligned rows)

// scan geometry
constexpr int SC_ELEM = 1024;
constexpr int SC_NB   = (cN_HIGH + SC_ELEM - 1) / SC_ELEM;     // 147
static_assert(SC_NB <= 256, "top scan assumes <=256 partials");

// ---------------- workspace layout (4-byte element offsets) ----------------
constexpr size_t OFF_HS   = 0;                                   // [N_LOW*628]
constexpr size_t SZ_HS    = (size_t)cN_LOW * cHSP;
constexpr size_t OFF_AGG  = 0;                                   // alias (hs dead after k_dense)
constexpr size_t OFF_ENC  = OFF_HS + SZ_HS;                      // [N_LOW*32]
constexpr size_t SZ_ENC   = (size_t)cN_LOW * cENC;
constexpr size_t OFF_XA   = OFF_ENC + SZ_ENC;
constexpr size_t OFF_XB   = OFF_XA + (size_t)cN_HIGH * cD;
constexpr size_t OFF_XL   = OFF_XB + (size_t)cN_HIGH * cD;
constexpr size_t OFF_XR   = OFF_XL + (size_t)cN_HIGH * cD;
constexpr size_t OFF_STAT = OFF_XR + (size_t)cN_HIGH * cD;       // [256]
constexpr size_t OFF_RPH  = OFF_STAT + 256;                      // rowptr_hh [N_HIGH+4]
constexpr size_t OFF_SRH  = OFF_RPH + cN_HIGH + 4;               // src_hh [E_HH]
constexpr size_t OFF_RPL  = OFF_SRH + cE_HH;                     // rowptr_l2h [N_HIGH+4]
constexpr size_t OFF_SRL  = OFF_RPL + cN_HIGH + 4;               // src_l2h [E_L2H]
constexpr size_t OFF_CUR  = OFF_SRL + cE_L2H;                    // cursor [N_HIGH]
constexpr size_t OFF_PART = OFF_CUR + cN_HIGH;                   // partials [256]

__device__ __forceinline__ float fast_sigmoid(float a) {
  return __builtin_amdgcn_rcpf(1.0f + __expf(-a));
}
__device__ __forceinline__ float fast_tanh(float a) {
  float t = __expf(-2.0f * a);
  return (1.0f - t) * __builtin_amdgcn_rcpf(1.0f + t);
}

// ---------------- GRU kernel ----------------
// Weights live in VGPRs (150/thread). Only x/h in LDS, double-buffered,
// 1 barrier/timestep. (r5->r6: 237 -> <160 us, out of top-5.)
constexpr int GRU_NODES = 10;
constexpr int GRU_BLOCK = GRU_NODES * cHHID;   // 250

__global__ __launch_bounds__(256, 2)
void k_gru(const float* __restrict__ x_low,
           const float* __restrict__ Wih, const float* __restrict__ Whh,
           const float* __restrict__ bih, const float* __restrict__ bhh,
           float* __restrict__ hs) {
  __shared__ float sx[2][GRU_NODES][cHIN];
  __shared__ float sh[2][GRU_NODES][cHHID];

  int tid = threadIdx.x;
  int nl = tid / cHHID;           // 0..9
  int j  = tid % cHHID;           // 0..24
  int n  = blockIdx.x * GRU_NODES + nl;

  float wr[25], wz[25], wn[25], ur[25], uz[25], un[25];
  #pragma unroll
  for (int i = 0; i < 25; ++i) {
    wr[i] = Wih[j * 25 + i];
    wz[i] = Wih[(25 + j) * 25 + i];
    wn[i] = Wih[(50 + j) * 25 + i];
    ur[i] = Whh[j * 25 + i];
    uz[i] = Whh[(25 + j) * 25 + i];
    un[i] = Whh[(50 + j) * 25 + i];
  }
  float br = bih[j], bz = bih[25 + j], bn2 = bih[50 + j];
  float cr = bhh[j], cz = bhh[25 + j], cn = bhh[50 + j];

  const float* xrow = x_low + (size_t)n * 625;
  float* hrow = hs + (size_t)n * cHSP;
  if (j < 3) hrow[625 + j] = 0.0f;       // zero hs row pad for dense float4 reads

  sh[0][nl][j] = 0.0f;
  sx[0][nl][j] = xrow[j];                // x for t=0
  __syncthreads();

  int p = 0;
  int q = 0;
  for (int t = 0; t < cSEQ; ++t) {
    if (t + 1 < cSEQ) sx[q ^ 1][nl][j] = xrow[(t + 1) * 25 + j];
    float gr = br + cr, gz = bz + cz, gni = bn2, gnh = cn;
    #pragma unroll
    for (int i = 0; i < 25; ++i) {
      float xv = sx[q][nl][i];
      float hv = sh[p][nl][i];
      gr  += wr[i] * xv + ur[i] * hv;
      gz  += wz[i] * xv + uz[i] * hv;
      gni += wn[i] * xv;
      gnh += un[i] * hv;
    }
    float r = fast_sigmoid(gr);
    float z = fast_sigmoid(gz);
    float nn = fast_tanh(gni + r * gnh);
    float hnew = (1.0f - z) * nn + z * sh[p][nl][j];
    sh[p ^ 1][nl][j] = hnew;
    hrow[t * 25 + j] = hnew;
    p ^= 1;
    q ^= 1;
    __syncthreads();
  }
}

// ---------------- dense 625->32 + relu + BN stats ----------------
// 32 nodes/block, thread = (channel e, node-group of 4): each ds_read_b128 of
// W feeds 16 FMAs (4x LDS-pipe amortization), 4 independent global chains for
// latency hiding, W staged once per 32 nodes (was per 8). r6: 161us, 1 out/thr.
__global__ __launch_bounds__(256)
void k_dense(const float* __restrict__ hs, const float* __restrict__ W,
             const float* __restrict__ b, float* __restrict__ enc,
             float* __restrict__ statsEnc) {
  __shared__ __align__(16) float sW[cENC * cHSP];    // 80.4 KB
  __shared__ float sstat[2 * cENC];
  int tid = threadIdx.x;
  for (int i = tid; i < cENC * 625; i += 256) {
    int e2 = i / 625, f2 = i % 625;
    sW[e2 * cHSP + f2] = W[i];
  }
  if (tid < cENC * 3) { int e2 = tid / 3; sW[e2 * cHSP + 625 + tid % 3] = 0.0f; }
  if (tid < 2 * cENC) sstat[tid] = 0.0f;
  __syncthreads();

  int e  = tid & 31;
  int g  = tid >> 5;                    // 0..7
  int n0 = blockIdx.x * 32 + g * 4;
  const float4* H0 = (const float4*)(hs + (size_t)(n0 + 0) * cHSP);
  const float4* H1 = (const float4*)(hs + (size_t)(n0 + 1) * cHSP);
  const float4* H2 = (const float4*)(hs + (size_t)(n0 + 2) * cHSP);
  const float4* H3 = (const float4*)(hs + (size_t)(n0 + 3) * cHSP);
  const float4* W4 = (const float4*)(sW + (size_t)e * cHSP);
  float a0 = 0.0f, a1 = 0.0f, a2 = 0.0f, a3 = 0.0f;
  #pragma unroll 2
  for (int f = 0; f < cHSP / 4; ++f) {
    float4 w = W4[f];
    float4 h0 = H0[f], h1 = H1[f], h2 = H2[f], h3 = H3[f];
    a0 += w.x * h0.x + w.y * h0.y + w.z * h0.z + w.w * h0.w;
    a1 += w.x * h1.x + w.y * h1.y + w.z * h1.z + w.w * h1.w;
    a2 += w.x * h2.x + w.y * h2.y + w.z * h2.z + w.w * h2.w;
    a3 += w.x * h3.x + w.y * h3.y + w.z * h3.z + w.w * h3.w;
  }
  float bb = b[e];
  float v0 = fmaxf(a0 + bb, 0.0f);
  float v1 = fmaxf(a1 + bb, 0.0f);
  float v2 = fmaxf(a2 + bb, 0.0f);
  float v3 = fmaxf(a3 + bb, 0.0f);
  enc[(size_t)(n0 + 0) * cENC + e] = v0;
  enc[(size_t)(n0 + 1) * cENC + e] = v1;
  enc[(size_t)(n0 + 2) * cENC + e] = v2;
  enc[(size_t)(n0 + 3) * cENC + e] = v3;

  float p = v0 + v1 + v2 + v3;
  float q = v0 * v0 + v1 * v1 + v2 * v2 + v3 * v3;
  p += __shfl_down(p, 32);
  q += __shfl_down(q, 32);
  if ((tid & 63) < 32) { atomicAdd(&sstat[e], p); atomicAdd(&sstat[cENC + e], q); }
  __syncthreads();
  if (tid < 2 * cENC) atomicAdd(&statsEnc[tid], sstat[tid]);
}

// ---------------- CSR build ----------------
__global__ void k_hist(const int* __restrict__ dst, int nE, int* __restrict__ cnt) {
  int e = blockIdx.x * 256 + threadIdx.x;
  if (e < nE) atomicAdd(&cnt[dst[e]], 1);
}

__global__ void k_scan_local(const int* __restrict__ deg, int n,
                             int* __restrict__ out, int* __restrict__ partial) {
  int tid = threadIdx.x;
  int base = blockIdx.x * SC_ELEM + tid * 4;
  int4 v = make_int4(0, 0, 0, 0);
  if (base + 3 < n) v = *(const int4*)(deg + base);
  else { int* pv = (int*)&v; for (int k = 0; k < 4; ++k) if (base + k < n) pv[k] = deg[base + k]; }
  int tsum = v.x + v.y + v.z + v.w;
  int lane = tid & 63;
  int inc = tsum;
  #pragma unroll
  for (int o = 1; o < 64; o <<= 1) { int t = __shfl_up(inc, o); if (lane >= o) inc += t; }
  __shared__ int wtot[4];
  if (lane == 63) wtot[tid >> 6] = inc;
  __syncthreads();
  int w = tid >> 6, wbase = 0;
  #pragma unroll
  for (int k = 0; k < 3; ++k) if (k < w) wbase += wtot[k];
  int ebase = wbase + inc - tsum;
  int4 o4;
  o4.x = ebase; o4.y = ebase + v.x; o4.z = o4.y + v.y; o4.w = o4.z + v.z;
  if (base + 3 < n) *(int4*)(out + base) = o4;
  else { int* po = (int*)&o4; for (int k = 0; k < 4; ++k) if (base + k < n) out[base + k] = po[k]; }
  if (tid == 255) partial[blockIdx.x] = wbase + inc;
}

__global__ void k_scan_top(int* __restrict__ partial, int nb, int* __restrict__ total_out) {
  __shared__ int sd[256];
  int tid = threadIdx.x;
  int v = (tid < nb) ? partial[tid] : 0;
  sd[tid] = v;
  __syncthreads();
  for (int off = 1; off < 256; off <<= 1) {
    int t = (tid >= off) ? sd[tid - off] : 0;
    __syncthreads();
    sd[tid] += t;
    __syncthreads();
  }
  if (tid < nb) partial[tid] = sd[tid] - v;
  if (tid == 255) *total_out = sd[255];
}

__global__ void k_scan_add(int* __restrict__ rowptr, const int* __restrict__ partial,
                           int n, int* __restrict__ cursor) {
  int base = blockIdx.x * SC_ELEM + threadIdx.x * 4;
  int add = partial[blockIdx.x];
  if (base + 3 < n) {
    int4 v = *(int4*)(rowptr + base);
    v.x += add; v.y += add; v.z += add; v.w += add;
    *(int4*)(rowptr + base) = v;
    *(int4*)(cursor + base) = v;
  } else {
    for (int k = 0; k < 4; ++k)
      if (base + k < n) { int t = rowptr[base + k] + add; rowptr[base + k] = t; cursor[base + k] = t; }
  }
}

__global__ void k_scatter(const int* __restrict__ src, const int* __restrict__ dst, int nE,
                          int* __restrict__ cursor, int* __restrict__ out) {
  int e = blockIdx.x * 256 + threadIdx.x;
  if (e < nE) {
    int pos = atomicAdd(&cursor[dst[e]], 1);
    out[pos] = src[e];
  }
}

// ---------------- l2h gather via CSR ----------------
__global__ void k_gather_csr(const float* __restrict__ enc, const int* __restrict__ rowptr,
                             const int* __restrict__ srcs, const float* __restrict__ statsEnc,
                             const float* __restrict__ g, const float* __restrict__ bb,
                             float* __restrict__ agg) {
  __shared__ float ssc[cENC], ssh[cENC];
  int tid = threadIdx.x;
  if (tid < cENC) {
    float m = statsEnc[tid] * INV_NLOW;
    float var = statsEnc[cENC + tid] * INV_NLOW - m * m;
    float sc = g[tid] * rsqrtf(var + cEPS);
    ssc[tid] = sc;
    ssh[tid] = bb[tid] - m * sc;
  }
  __syncthreads();
  int c = tid & 31;
  int n = blockIdx.x * 8 + (tid >> 5);
  int lo = rowptr[n], hi = rowptr[n + 1];
  float sum = 0.0f;
  for (int i = lo; i < hi; ++i) {
    int s = srcs[i];
    sum += enc[(size_t)s * cENC + c];
  }
  float deg = (float)(hi - lo);
  agg[(size_t)n * cENC + c] = (ssc[c] * sum + deg * ssh[c]) / fmaxf(deg, 1.0f);
}

// ---------------- down-projection + BN0 stats ----------------
__global__ void k_down(const float* __restrict__ agg,
                       const float* __restrict__ z_std, const float* __restrict__ land,
                       const float* __restrict__ Wrel, const float* __restrict__ brel,
                       const float* __restrict__ Wroot,
                       float* __restrict__ x0, float* __restrict__ stats) {
  __shared__ float sstat[2 * cD];
  __shared__ float sWrel[cD * cENC], sWroot[cD * cHIGH_IN], sbrel[cD];
  int tid = threadIdx.x;
  if (tid < 2 * cD) sstat[tid] = 0.0f;
  for (int i = tid; i < cD * cENC; i += 256) sWrel[i] = Wrel[i];
  if (tid < cD * cHIGH_IN) sWroot[tid] = Wroot[tid];
  if (tid < cD) sbrel[tid] = brel[tid];
  __syncthreads();

  int n = blockIdx.x * 256 + tid;
  bool valid = n < cN_HIGH;
  float a[cENC], zz[cHIGH_IN];
  if (valid) {
    const float4* ar4 = (const float4*)(agg + (size_t)n * cENC);
    #pragma unroll
    for (int k = 0; k < cENC / 4; ++k) {
      float4 t4 = ar4[k];
      a[4*k] = t4.x; a[4*k+1] = t4.y; a[4*k+2] = t4.z; a[4*k+3] = t4.w;
    }
    #pragma unroll
    for (int k = 0; k < 6; ++k) zz[k] = z_std[(size_t)n * 6 + k];
    zz[6] = land[n];
  } else {
    #pragma unroll
    for (int k = 0; k < cENC; ++k) a[k] = 0.0f;
    #pragma unroll
    for (int k = 0; k < cHIGH_IN; ++k) zz[k] = 0.0f;
  }
  int lane = tid & 63;
  #pragma unroll
  for (int d = 0; d < cD; ++d) {
    float acc = sbrel[d];
    #pragma unroll
    for (int k = 0; k < cENC; ++k) acc += a[k] * sWrel[d * cENC + k];
    #pragma unroll
    for (int k = 0; k < cHIGH_IN; ++k) acc += zz[k] * sWroot[d * cHIGH_IN + k];
    if (valid) x0[(size_t)n * cD + d] = acc;
    float v = valid ? acc : 0.0f;
    float s1 = v, s2 = v * v;
    #pragma unroll
    for (int o = 32; o > 0; o >>= 1) { s1 += __shfl_down(s1, o); s2 += __shfl_down(s2, o); }
    if (lane == 0) { atomicAdd(&sstat[d], s1); atomicAdd(&sstat[cD + d], s2); }
  }
  __syncthreads();
  if (tid < 2 * cD) atomicAdd(&stats[tid], sstat[tid]);
}

// ---------------- GAT node transform ----------------
__global__ void k_transform(const float* __restrict__ xin, const float* __restrict__ stats,
                            const float* __restrict__ g, const float* __restrict__ b,
                            const float* __restrict__ Wl, const float* __restrict__ bl,
                            const float* __restrict__ Wr, const float* __restrict__ br,
                            int applyRelu,
                            float* __restrict__ xl, float* __restrict__ xr) {
  __shared__ float ssc[cD], ssh[cD], sWl[cD * cD], sWr[cD * cD], sbl[cD], sbr[cD];
  int tid = threadIdx.x;
  if (tid < cD) {
    float m = stats[tid] * INV_NHIGH;
    float v = stats[cD + tid] * INV_NHIGH - m * m;
    float sc = g[tid] * rsqrtf(v + cEPS);
    ssc[tid] = sc;
    ssh[tid] = b[tid] - m * sc;
    sbl[tid] = bl[tid];
    sbr[tid] = br[tid];
  }
  if (tid < cD * cD) { sWl[tid] = Wl[tid]; sWr[tid] = Wr[tid]; }
  __syncthreads();

  int n = blockIdx.x * 256 + tid;
  if (n >= cN_HIGH) return;
  float act[cD];
  const float* xp = xin + (size_t)n * cD;
  #pragma unroll
  for (int d = 0; d < cD; ++d) {
    float v = xp[d] * ssc[d] + ssh[d];
    if (applyRelu) v = fmaxf(v, 0.0f);
    act[d] = v;
  }
  float* xlp = xl + (size_t)n * cD;
  float* xrp = xr + (size_t)n * cD;
  #pragma unroll
  for (int d = 0; d < cD; ++d) {
    float al = sbl[d], ar = sbr[d];
    #pragma unroll
    for (int k = 0; k < cD; ++k) { al += act[k] * sWl[d * cD + k]; ar += act[k] * sWr[d * cD + k]; }
    xlp[d] = al;
    xrp[d] = ar;
  }
}

// ---------------- fused GAT edge pass via CSR (4-way unrolled) ----------------
template<int FINAL>
__global__ void k_edge(const float* __restrict__ xl, const float* __restrict__ xr,
                       const int* __restrict__ rowptr, const int* __restrict__ srcs,
                       const float* __restrict__ att, const float* __restrict__ bias,
                       const float* __restrict__ pW, const float* __restrict__ pb,
                       float* __restrict__ xout, float* __restrict__ stats,
                       float* __restrict__ out) {
  __shared__ float satt[cD], sbias[cD];
  __shared__ float sstat[2 * cD];
  int tid = threadIdx.x;
  if (tid < cD) { satt[tid] = att[tid]; sbias[tid] = bias[tid]; }
  if (!FINAL && tid < 2 * cD) sstat[tid] = 0.0f;
  __syncthreads();

  int d = tid & 15;
  int n = blockIdx.x * 16 + (tid >> 4);
  float a_d = satt[d];
  float xr_d = xr[(size_t)n * cD + d];
  float xl_self = xl[(size_t)n * cD + d];

  float v = xl_self + xr_d;
  v = v > 0.0f ? v : cSLOPE * v;
  float p = v * a_d;
  p += __shfl_xor(p, 1); p += __shfl_xor(p, 2); p += __shfl_xor(p, 4); p += __shfl_xor(p, 8);
  float ex = __expf(p);
  float denom = ex;
  float num = ex * xl_self;

  int lo = rowptr[n], hi = rowptr[n + 1];
  int i = lo;
  for (; i + 3 < hi; i += 4) {
    int s0 = srcs[i], s1 = srcs[i + 1], s2 = srcs[i + 2], s3 = srcs[i + 3];
    float x0 = xl[(size_t)s0 * cD + d];
    float x1 = xl[(size_t)s1 * cD + d];
    float x2 = xl[(size_t)s2 * cD + d];
    float x3 = xl[(size_t)s3 * cD + d];
    float w0 = x0 + xr_d; w0 = w0 > 0.0f ? w0 : cSLOPE * w0;
    float w1 = x1 + xr_d; w1 = w1 > 0.0f ? w1 : cSLOPE * w1;
    float w2 = x2 + xr_d; w2 = w2 > 0.0f ? w2 : cSLOPE * w2;
    float w3 = x3 + xr_d; w3 = w3 > 0.0f ? w3 : cSLOPE * w3;
    float q0 = w0 * a_d, q1 = w1 * a_d, q2 = w2 * a_d, q3 = w3 * a_d;
    q0 += __shfl_xor(q0, 1); q1 += __shfl_xor(q1, 1); q2 += __shfl_xor(q2, 1); q3 += __shfl_xor(q3, 1);
    q0 += __shfl_xor(q0, 2); q1 += __shfl_xor(q1, 2); q2 += __shfl_xor(q2, 2); q3 += __shfl_xor(q3, 2);
    q0 += __shfl_xor(q0, 4); q1 += __shfl_xor(q1, 4); q2 += __shfl_xor(q2, 4); q3 += __shfl_xor(q3, 4);
    q0 += __shfl_xor(q0, 8); q1 += __shfl_xor(q1, 8); q2 += __shfl_xor(q2, 8); q3 += __shfl_xor(q3, 8);
    float e0 = __expf(q0), e1 = __expf(q1), e2c = __expf(q2), e3 = __expf(q3);
    denom += (e0 + e1) + (e2c + e3);
    num += e0 * x0 + e1 * x1 + e2c * x2 + e3 * x3;
  }
  for (; i < hi; ++i) {
    int s = srcs[i];
    float xls = xl[(size_t)s * cD + d];
    float w = xls + xr_d;
    w = w > 0.0f ? w : cSLOPE * w;
    float q = w * a_d;
    q += __shfl_xor(q, 1); q += __shfl_xor(q, 2); q += __shfl_xor(q, 4); q += __shfl_xor(q, 8);
    float e2 = __expf(q);
    denom += e2;
    num += e2 * xls;
  }
  float cnt = (float)(hi - lo + 1);
  float res = num / denom / cnt + sbias[d];

  if (FINAL) {
    float t = fmaxf(res, 0.0f) * pW[d];
    t += __shfl_xor(t, 1); t += __shfl_xor(t, 2); t += __shfl_xor(t, 4); t += __shfl_xor(t, 8);
    if (d == 0) out[n] = t + pb[0];
  } else {
    xout[(size_t)n * cD + d] = res;
    float s1 = res, s2 = res * res;
    s1 += __shfl_xor(s1, 16); s2 += __shfl_xor(s2, 16);
    s1 += __shfl_xor(s1, 32); s2 += __shfl_xor(s2, 32);
    if ((tid & 63) < 16) { atomicAdd(&sstat[d], s1); atomicAdd(&sstat[cD + d], s2); }
    __syncthreads();
    if (tid < 2 * cD) atomicAdd(&stats[tid], sstat[tid]);
  }
}

// ---------------- launch ----------------
extern "C" void kernel_launch(void* const* d_in, const int* in_sizes, int n_in,
                              void* d_out, int out_size, void* d_ws, size_t ws_size,
                              hipStream_t stream) {
  const float* x_low    = (const float*)d_in[0];
  const float* z_std    = (const float*)d_in[1];
  const float* land     = (const float*)d_in[2];
  const int*   l2h_src  = (const int*)d_in[3];
  const int*   l2h_dst  = (const int*)d_in[4];
  const int*   hh_src   = (const int*)d_in[5];
  const int*   hh_dst   = (const int*)d_in[6];
  const float* gWih     = (const float*)d_in[7];
  const float* gWhh     = (const float*)d_in[8];
  const float* gbih     = (const float*)d_in[9];
  const float* gbhh     = (const float*)d_in[10];
  const float* dW       = (const float*)d_in[11];
  const float* db       = (const float*)d_in[12];
  const float* bn_enc_g = (const float*)d_in[13];
  const float* bn_enc_b = (const float*)d_in[14];
  const float* Wrel     = (const float*)d_in[15];
  const float* brel     = (const float*)d_in[16];
  const float* Wroot    = (const float*)d_in[17];
  const float* gat_Wl   = (const float*)d_in[18];
  const float* gat_bl   = (const float*)d_in[19];
  const float* gat_Wr   = (const float*)d_in[20];
  const float* gat_br   = (const float*)d_in[21];
  const float* gat_att  = (const float*)d_in[22];
  const float* gat_bias = (const float*)d_in[23];
  const float* bn_g     = (const float*)d_in[24];
  const float* bn_b     = (const float*)d_in[25];
  const float* pred_W   = (const float*)d_in[26];
  const float* pred_b   = (const float*)d_in[27];

  float* ws = (float*)d_ws;
  float* hs   = ws + OFF_HS;
  float* agg  = ws + OFF_AGG;
  float* enc  = ws + OFF_ENC;
  float* xA   = ws + OFF_XA;
  float* xB   = ws + OFF_XB;
  float* xl   = ws + OFF_XL;
  float* xr   = ws + OFF_XR;
  float* statsEnc = ws + OFF_STAT;
  float* statsX   = ws + OFF_STAT + 64;
  int* rp_hh  = (int*)(ws + OFF_RPH);
  int* src_hh = (int*)(ws + OFF_SRH);
  int* rp_l2h = (int*)(ws + OFF_RPL);
  int* src_l2h= (int*)(ws + OFF_SRL);
  int* cursor = (int*)(ws + OFF_CUR);
  int* part   = (int*)(ws + OFF_PART);

  hipMemsetAsync(statsEnc, 0, 256 * sizeof(float), stream);

  // --- CSR build: hh ---
  hipMemsetAsync(cursor, 0, cN_HIGH * sizeof(int), stream);
  k_hist<<<(cE_HH + 255) / 256, 256, 0, stream>>>(hh_dst, cE_HH, cursor);
  k_scan_local<<<SC_NB, 256, 0, stream>>>(cursor, cN_HIGH, rp_hh, part);
  k_scan_top<<<1, 256, 0, stream>>>(part, SC_NB, rp_hh + cN_HIGH);
  k_scan_add<<<SC_NB, 256, 0, stream>>>(rp_hh, part, cN_HIGH, cursor);
  k_scatter<<<(cE_HH + 255) / 256, 256, 0, stream>>>(hh_src, hh_dst, cE_HH, cursor, src_hh);
  // --- CSR build: l2h ---
  hipMemsetAsync(cursor, 0, cN_HIGH * sizeof(int), stream);
  k_hist<<<(cE_L2H + 255) / 256, 256, 0, stream>>>(l2h_dst, cE_L2H, cursor);
  k_scan_local<<<SC_NB, 256, 0, stream>>>(cursor, cN_HIGH, rp_l2h, part);
  k_scan_top<<<1, 256, 0, stream>>>(part, SC_NB, rp_l2h + cN_HIGH);
  k_scan_add<<<SC_NB, 256, 0, stream>>>(rp_l2h, part, cN_HIGH, cursor);
  k_scatter<<<(cE_L2H + 255) / 256, 256, 0, stream>>>(l2h_src, l2h_dst, cE_L2H, cursor, src_l2h);

  // --- encoder ---
  k_gru<<<cN_LOW / GRU_NODES, GRU_BLOCK, 0, stream>>>(x_low, gWih, gWhh, gbih, gbhh, hs);
  k_dense<<<cN_LOW / 32, 256, 0, stream>>>(hs, dW, db, enc, statsEnc);
  k_gather_csr<<<cN_HIGH / 8, 256, 0, stream>>>(enc, rp_l2h, src_l2h, statsEnc,
                                                bn_enc_g, bn_enc_b, agg);
  const int NODE_GRID = (cN_HIGH + 255) / 256;
  k_down<<<NODE_GRID, 256, 0, stream>>>(agg, z_std, land, Wrel, brel, Wroot, xA, statsX);

  // --- 5 GATv2 layers ---
  for (int i = 0; i < cNL; ++i) {
    float* xin  = (i & 1) ? xB : xA;
    float* xout = (i & 1) ? xA : xB;
    k_transform<<<NODE_GRID, 256, 0, stream>>>(xin, statsX + 32 * i,
                                               bn_g + 16 * i, bn_b + 16 * i,
                                               gat_Wl + 256 * i, gat_bl + 16 * i,
                                               gat_Wr + 256 * i, gat_br + 16 * i,
                                               (i > 0) ? 1 : 0, xl, xr);
    if (i < cNL - 1) {
      k_edge<0><<<cN_HIGH / 16, 256, 0, stream>>>(xl, xr, rp_hh, src_hh,
                                                  gat_att + 16 * i, gat_bias + 16 * i,
                                                  nullptr, nullptr,
                                                  xout, statsX + 32 * (i + 1), nullptr);
    } else {
      k_edge<1><<<cN_HIGH / 16, 256, 0, stream>>>(xl, xr, rp_hh, src_hh,
                                                  gat_att + 16 * i, gat_bias + 16 * i,
                                                  pred_W, pred_b,
                                                  nullptr, nullptr, (float*)d_out);
    }
  }
}